// Round 9
// baseline (3331.209 us; speedup 1.0000x reference)
//
#include <hip/hip_runtime.h>
#include <hip/hip_bf16.h>

#define NPTS 8192
#define KNN  20
#define KC   4

__device__ __forceinline__ unsigned fkey(float f) {
  unsigned u = __float_as_uint(f);
  return (u & 0x80000000u) ? ~u : (u | 0x80000000u);
}
__device__ __forceinline__ float funkey(unsigned k) {
  return (k & 0x80000000u) ? __uint_as_float(k & 0x7fffffffu) : __uint_as_float(~k);
}
__device__ __forceinline__ float lrelu(float x) { return x >= 0.f ? x : 0.2f * x; }

// ---------------------------------------------------------------- prep weights
__global__ __launch_bounds__(256) void prep_kernel(
    const float* __restrict__ w1a, const float* __restrict__ w1b,
    const float* __restrict__ w2a, const float* __restrict__ w2b,
    const float* __restrict__ w3a, const float* __restrict__ wg,
    float* __restrict__ wp1A, float* __restrict__ wp1B,
    float* __restrict__ wp2A, float* __restrict__ wp2B,
    float* __restrict__ wp3A, float* __restrict__ wgT)
{
  const int t0 = blockIdx.x * blockDim.x + threadIdx.x;
  const int NT = gridDim.x * blockDim.x;
  for (int f = t0; f < 512; f += NT) {            // wp1A [2][64] f4, folded
    int i = f & 3, o = (f >> 2) & 63, c4 = f >> 8, c = c4 * 4 + i;
    float v = 0.f;
    if (c < 3)      v = w1a[o*12 + c]     + w1a[o*12 + c + 3];
    else if (c < 6) v = w1a[o*12 + c + 3] + w1a[o*12 + c + 6];
    wp1A[f] = v;
  }
  for (int f = t0; f < 4096; f += NT) {           // wp1B / wp2B [16][64] f4
    int i = f & 3, o = (f >> 2) & 63, c4 = f >> 8, c = c4 * 4 + i;
    wp1B[f] = w1b[o*64 + c];
    wp2B[f] = w2b[o*64 + c];
  }
  for (int f = t0; f < 8192; f += NT) {           // wp2A / wp3A [32][64] f4
    int i = f & 3, o = (f >> 2) & 63, c4 = f >> 8, c = c4 * 4 + i;
    wp2A[f] = w2a[o*128 + c];
    wp3A[f] = w3a[o*128 + c];
  }
  for (int f = t0; f < 192 * 1024; f += NT) {     // wgT [192][1024]
    int c = f >> 10, o = f & 1023;
    wgT[f] = wg[o*192 + c];
  }
}

// ---------------------------------------------------------------- point norms
__global__ __launch_bounds__(256) void xx_points(const float* __restrict__ pts,
                                                 float* __restrict__ xx)
{
  int t = blockIdx.x * 256 + threadIdx.x;
  if (t < 2 * NPTS) {
    const float* p = pts + (size_t)t * 3;
    xx[t] = p[0]*p[0] + p[1]*p[1] + p[2]*p[2];
  }
}

// ---------------------------------------------------------------- selection
// Halved top-20: one wave selects top-20 of one 4096-elem HALF of a row
// (chunks = 64x64). Chunk maxima in 1 reg/lane; butterfly-1 picks chunk
// (tie -> lower chunk); butterfly-2 carries (max, argmax, 2nd) so repair is
// free. Marks written by all lanes (same addr/value). Candidates go to LDS.
__device__ __forceinline__ void select20_half(float* __restrict__ sdrow, float cr,
                                              int half, int lane,
                                              float* __restrict__ cv, int* __restrict__ ci)
{
  const int jbase = half << 12;
  for (int kk = 0; kk < KNN; ++kk) {
    float bv = cr; int bc = lane;
    #pragma unroll
    for (int m = 32; m >= 1; m >>= 1) {
      float ov = __shfl_xor(bv, m); int oc = __shfl_xor(bc, m);
      if (ov > bv || (ov == bv && oc < bc)) { bv = ov; bc = oc; }
    }
    const int j = jbase + bc * 64 + lane;
    float v1 = sdrow[j]; int j1 = j; float v2 = -INFINITY;
    #pragma unroll
    for (int m = 32; m >= 1; m >>= 1) {
      float ov1 = __shfl_xor(v1, m); int oj1 = __shfl_xor(j1, m);
      float ov2 = __shfl_xor(v2, m);
      bool aw = (v1 > ov1) || (v1 == ov1 && j1 < oj1);
      float nv2 = aw ? fmaxf(v2, ov1) : fmaxf(ov2, v1);
      v1 = aw ? v1 : ov1; j1 = aw ? j1 : oj1; v2 = nv2;
    }
    if (lane == 0) { cv[kk] = v1; ci[kk] = j1; }
    sdrow[j1] = -INFINITY;
    if (lane == bc) cr = v2;
  }
}

// Merge 2x20 candidates (register-resident, pure shuffle): 20 extractions,
// tie -> lower index == lax.top_k order. Winner pops itself via idx match.
__device__ __forceinline__ void merge40(const float* __restrict__ cv,
                                        const int* __restrict__ ci,
                                        int lane, int* __restrict__ orow)
{
  float v = (lane < 40) ? cv[lane] : -INFINITY;
  int   i = (lane < 40) ? ci[lane] : 0x7fffffff;
  for (int kk = 0; kk < KNN; ++kk) {
    float bv = v; int bi = i;
    #pragma unroll
    for (int m = 32; m >= 1; m >>= 1) {
      float ov = __shfl_xor(bv, m); int oi = __shfl_xor(bi, m);
      if (ov > bv || (ov == bv && oi < bi)) { bv = ov; bi = oi; }
    }
    if (lane == 0) orow[kk] = bi;
    if (i == bi) v = -INFINITY;
  }
}

// ---------------------------------------------------------------- kNN on xyz
// 512 threads (8 waves = 2/SIMD), 4 rows/block. Selection: 8 waves, one per
// (row, half); then 4 waves merge.
__global__ __launch_bounds__(512, 2) void knn3_kernel(
    const float* __restrict__ pts, const float* __restrict__ xx,
    int* __restrict__ idxout)
{
  __shared__ __align__(16) float sd[4][NPTS];          // 128 KB
  __shared__ float s_ctr[4][4];
  __shared__ float s_cmax[4][128];
  __shared__ float s_cv[4][40];
  __shared__ int   s_ci[4][40];
  const int tid = threadIdx.x;
  const int b   = blockIdx.x / (NPTS / 4);
  const int r0  = (blockIdx.x % (NPTS / 4)) * 4;
  const size_t rowbase = (size_t)b * NPTS;

  for (int i = tid; i < 12; i += 512)
    s_ctr[i / 3][i % 3] = pts[(rowbase + r0 + i / 3) * 3 + i % 3];
  __syncthreads();

  const float xr0 = xx[rowbase + r0 + 0], xr1 = xx[rowbase + r0 + 1];
  const float xr2 = xx[rowbase + r0 + 2], xr3 = xx[rowbase + r0 + 3];
  const float c00 = s_ctr[0][0], c01 = s_ctr[0][1], c02 = s_ctr[0][2];
  const float c10 = s_ctr[1][0], c11 = s_ctr[1][1], c12 = s_ctr[1][2];
  const float c20 = s_ctr[2][0], c21 = s_ctr[2][1], c22 = s_ctr[2][2];
  const float c30 = s_ctr[3][0], c31 = s_ctr[3][1], c32 = s_ctr[3][2];

  for (int j = tid; j < NPTS; j += 512) {
    const float* fj = pts + (rowbase + j) * 3;
    const float f0 = fj[0], f1 = fj[1], f2 = fj[2];
    const float xj = xx[rowbase + j];
    sd[0][j] = 2.f*(f0*c00 + f1*c01 + f2*c02) - xr0 - xj;
    sd[1][j] = 2.f*(f0*c10 + f1*c11 + f2*c12) - xr1 - xj;
    sd[2][j] = 2.f*(f0*c20 + f1*c21 + f2*c22) - xr2 - xj;
    sd[3][j] = 2.f*(f0*c30 + f1*c31 + f2*c32) - xr3 - xj;
  }
  __syncthreads();

  { // chunk maxima: 512 threads x 1 chunk; diagonal order -> conflict-free
    const int rr = tid >> 7, c = tid & 127;
    float m = -INFINITY;
    for (int t = 0; t < 64; ++t)
      m = fmaxf(m, sd[rr][(c << 6) + ((t + c) & 63)]);
    s_cmax[rr][c] = m;
  }
  __syncthreads();

  const int wid = tid >> 6, lane = tid & 63;
  const int row = wid >> 1, half = wid & 1;
  select20_half(sd[row], s_cmax[row][half * 64 + lane], half, lane,
                &s_cv[row][half * 20], &s_ci[row][half * 20]);
  __syncthreads();
  if (wid < 4)
    merge40(s_cv[wid], s_ci[wid], lane, idxout + (rowbase + r0 + wid) * KNN);
}

// ---------------------------------------------------------------- kNN on 64-ch features
// featT channel-major [b][64][8192]: lane=point -> coalesced 1KB wave reads.
// 512 threads, launch_bounds(512,2) -> VGPR cap 256 (the default 128-cap
// caused the R6 spill). unroll 4 keeps ~16 outstanding loads at ~132 VGPR.
// XCD swizzle pins each XCD to one batch's 2MB panel (L2-resident).
#define ACC4(A, C) \
  A.x += v0.x*C.x + v1.x*C.y + v2.x*C.z + v3.x*C.w; \
  A.y += v0.y*C.x + v1.y*C.y + v2.y*C.z + v3.y*C.w; \
  A.z += v0.z*C.x + v1.z*C.y + v2.z*C.z + v3.z*C.w; \
  A.w += v0.w*C.x + v1.w*C.y + v2.w*C.z + v3.w*C.w;

__global__ __launch_bounds__(512, 2) void knn64_kernel(
    const float* __restrict__ featT, const float* __restrict__ xx,
    int* __restrict__ idxout)
{
  __shared__ __align__(16) float sd[4][NPTS];          // 128 KB
  __shared__ __align__(16) float s_ctr[4][64];
  __shared__ float s_cmax[4][128];
  __shared__ float s_cv[4][40];
  __shared__ int   s_ci[4][40];
  const int tid = threadIdx.x;
  const int bid = blockIdx.x;
  const int b   = (bid & 7) >> 2;                      // XCD-batch swizzle
  const int r0  = (((bid >> 3) << 2) + (bid & 3)) * 4; // bijective rowgrp
  const size_t tb = (size_t)b * 64 * NPTS;
  const size_t rowbase = (size_t)b * NPTS;

  if (tid < 256)
    s_ctr[tid >> 6][tid & 63] = featT[tb + (size_t)(tid & 63) * NPTS + r0 + (tid >> 6)];
  __syncthreads();

  const int wid = tid >> 6, lane = tid & 63;
  const float xr0 = xx[rowbase + r0 + 0], xr1 = xx[rowbase + r0 + 1];
  const float xr2 = xx[rowbase + r0 + 2], xr3 = xx[rowbase + r0 + 3];
  const float4* ct0 = (const float4*)s_ctr[0];
  const float4* ct1 = (const float4*)s_ctr[1];
  const float4* ct2 = (const float4*)s_ctr[2];
  const float4* ct3 = (const float4*)s_ctr[3];

  #pragma unroll 1
  for (int ch = 0; ch < 4; ++ch) {
    const int jb = (wid << 10) + (ch << 8) + (lane << 2);   // 4 points per lane
    float4 a0 = {0.f,0.f,0.f,0.f}, a1 = a0, a2 = a0, a3 = a0;
    const float* fp0 = featT + tb + jb;
    #pragma unroll 4
    for (int c4 = 0; c4 < 16; ++c4) {
      const float* fp = fp0 + (size_t)(c4 * 4) * NPTS;
      float4 v0 = *(const float4*)(fp);
      float4 v1 = *(const float4*)(fp + NPTS);
      float4 v2 = *(const float4*)(fp + 2 * NPTS);
      float4 v3 = *(const float4*)(fp + 3 * NPTS);
      float4 c0 = ct0[c4], c1 = ct1[c4], c2 = ct2[c4], c3 = ct3[c4];
      ACC4(a0, c0); ACC4(a1, c1); ACC4(a2, c2); ACC4(a3, c3);
    }
    const float4 xv = *(const float4*)(xx + rowbase + jb);
    float4 s0, s1, s2, s3;
    s0.x = 2.f*a0.x - xr0 - xv.x; s0.y = 2.f*a0.y - xr0 - xv.y;
    s0.z = 2.f*a0.z - xr0 - xv.z; s0.w = 2.f*a0.w - xr0 - xv.w;
    s1.x = 2.f*a1.x - xr1 - xv.x; s1.y = 2.f*a1.y - xr1 - xv.y;
    s1.z = 2.f*a1.z - xr1 - xv.z; s1.w = 2.f*a1.w - xr1 - xv.w;
    s2.x = 2.f*a2.x - xr2 - xv.x; s2.y = 2.f*a2.y - xr2 - xv.y;
    s2.z = 2.f*a2.z - xr2 - xv.z; s2.w = 2.f*a2.w - xr2 - xv.w;
    s3.x = 2.f*a3.x - xr3 - xv.x; s3.y = 2.f*a3.y - xr3 - xv.y;
    s3.z = 2.f*a3.z - xr3 - xv.z; s3.w = 2.f*a3.w - xr3 - xv.w;
    *(float4*)&sd[0][jb] = s0;
    *(float4*)&sd[1][jb] = s1;
    *(float4*)&sd[2][jb] = s2;
    *(float4*)&sd[3][jb] = s3;
  }
  __syncthreads();

  { // chunk maxima: 512 threads x 1 chunk; diagonal -> conflict-free
    const int rr = tid >> 7, c = tid & 127;
    float m = -INFINITY;
    for (int t = 0; t < 64; ++t)
      m = fmaxf(m, sd[rr][(c << 6) + ((t + c) & 63)]);
    s_cmax[rr][c] = m;
  }
  __syncthreads();

  const int row = wid >> 1, half = wid & 1;
  select20_half(sd[row], s_cmax[row][half * 64 + lane], half, lane,
                &s_cv[row][half * 20], &s_ci[row][half * 20]);
  __syncthreads();
  if (wid < 4)
    merge40(s_cv[wid], s_ci[wid], lane, idxout + (rowbase + r0 + wid) * KNN);
}

// ---------------------------------------------------------------- fused EdgeConv
// Block = 4 points x 64 channels (wave = one point). WAUX: also writes xx
// (feature norms for next kNN) and the channel-major featT panel.
template<int D, bool HASB, bool WAUX>
__global__ __launch_bounds__(256) void fused_conv(
    const float* __restrict__ feat, int fstride, int foff,
    const int* __restrict__ idx,
    const float4* __restrict__ wAp, const float* __restrict__ sa, const float* __restrict__ ba,
    const float4* __restrict__ wBp, const float* __restrict__ sb, const float* __restrict__ bb,
    float* __restrict__ outbuf, int ooff, float* __restrict__ xxout,
    float* __restrict__ featT)
{
  constexpr int CHA  = (D == 64) ? 32 : 2;   // float4 chunks of 2D (padded)
  constexpr int CHA4 = CHA * 4;
  __shared__ float4 s_wA[CHA * 64];
  __shared__ float4 s_wB[HASB ? 16 * 64 : 1];
  __shared__ __align__(16) float4 s_g[4 * KC * CHA];
  __shared__ __align__(16) float  s_h1[HASB ? 4 * KC * 64 : 4];
  __shared__ float s_ctr[4][(D > 4) ? D : 4];
  __shared__ float s_sa[64], s_ba[64], s_sb[64], s_bb[64];

  const int tid = threadIdx.x;
  const int p = tid >> 6, o = tid & 63;
  const int b  = blockIdx.x / (NPTS / 4);
  const int p0 = (blockIdx.x % (NPTS / 4)) * 4;
  const size_t rowbase = (size_t)b * NPTS;

  for (int i = tid; i < CHA * 64; i += 256) s_wA[i] = wAp[i];
  if (HASB) for (int i = tid; i < 16 * 64; i += 256) s_wB[i] = wBp[i];
  if (tid < 64) {
    s_sa[tid] = sa[tid]; s_ba[tid] = ba[tid];
    if (HASB) { s_sb[tid] = sb[tid]; s_bb[tid] = bb[tid]; }
  }
  for (int i = tid; i < 4 * D; i += 256)
    s_ctr[i / D][i % D] = feat[(rowbase + p0 + (i / D)) * fstride + foff + (i % D)];
  __syncthreads();

  float* s_gf = (float*)s_g;
  float hmax = -INFINITY;
  for (int kc = 0; kc < KNN / KC; ++kc) {
    for (int s = tid; s < 4 * KC * CHA4; s += 256) {
      int pp = s / (KC * CHA4);
      int rr = s - pp * (KC * CHA4);
      int kk = rr / CHA4;
      int c  = rr - kk * CHA4;
      int nb = idx[(rowbase + p0 + pp) * KNN + kc * KC + kk];
      float v;
      if (D == 64) {
        v = (c < 64) ? (feat[(rowbase + nb) * fstride + foff + c] - s_ctr[pp][c])
                     : s_ctr[pp][c - 64];
      } else {
        if (c < 3)      v = feat[(rowbase + nb) * 3 + c] - s_ctr[pp][c];
        else if (c < 6) v = s_ctr[pp][c - 3];
        else            v = 0.f;
      }
      s_gf[s] = v;
    }
    __syncthreads();

    float acc[KC];
    #pragma unroll
    for (int kk = 0; kk < KC; ++kk) acc[kk] = 0.f;
    for (int c4 = 0; c4 < CHA; ++c4) {
      float4 w = s_wA[c4 * 64 + o];
      #pragma unroll
      for (int kk = 0; kk < KC; ++kk) {
        float4 g = s_g[(p * KC + kk) * CHA + c4];
        acc[kk] += w.x*g.x + w.y*g.y + w.z*g.z + w.w*g.w;
      }
    }
    if (HASB) {
      #pragma unroll
      for (int kk = 0; kk < KC; ++kk)
        s_h1[(p * KC + kk) * 64 + o] = lrelu(acc[kk] * s_sa[o] + s_ba[o]);
      __syncthreads();
      float acc2[KC];
      #pragma unroll
      for (int kk = 0; kk < KC; ++kk) acc2[kk] = 0.f;
      const float4* s_h14 = (const float4*)s_h1;
      for (int c4 = 0; c4 < 16; ++c4) {
        float4 w = s_wB[c4 * 64 + o];
        #pragma unroll
        for (int kk = 0; kk < KC; ++kk) {
          float4 h = s_h14[(p * KC + kk) * 16 + c4];
          acc2[kk] += w.x*h.x + w.y*h.y + w.z*h.z + w.w*h.w;
        }
      }
      #pragma unroll
      for (int kk = 0; kk < KC; ++kk)
        hmax = fmaxf(hmax, lrelu(acc2[kk] * s_sb[o] + s_bb[o]));
      __syncthreads();
    } else {
      #pragma unroll
      for (int kk = 0; kk < KC; ++kk)
        hmax = fmaxf(hmax, lrelu(acc[kk] * s_sa[o] + s_ba[o]));
      __syncthreads();
    }
  }
  outbuf[(rowbase + p0 + p) * 192 + ooff + o] = hmax;
  if (WAUX) {
    featT[(size_t)b * 64 * NPTS + (size_t)o * NPTS + (p0 + p)] = hmax;
    float ss = hmax * hmax;
    #pragma unroll
    for (int m = 1; m < 64; m <<= 1) ss += __shfl_xor(ss, m);
    if (o == 0) xxout[rowbase + p0 + p] = ss;
  }
}

// ---------------------------------------------------------------- final 192->1024
__global__ __launch_bounds__(256) void init_gmax(unsigned* __restrict__ g)
{
  int t = blockIdx.x * 256 + threadIdx.x;
  if (t < 2048) g[t] = fkey(-1e30f);
}

__global__ __launch_bounds__(256) void final_kernel(
    const float* __restrict__ cat, const float* __restrict__ wgT,
    const float* __restrict__ sg, const float* __restrict__ bg,
    unsigned* __restrict__ gmax)
{
  const int tid = threadIdx.x;
  const int chunk = blockIdx.x & 15;
  const int grp   = blockIdx.x >> 4;
  const int pt = grp * 256 + tid;
  const int b  = pt >> 13;
  const float4* crow = (const float4*)(cat + (size_t)pt * 192);
  float acc[64];
  #pragma unroll
  for (int o = 0; o < 64; ++o) acc[o] = 0.f;
  for (int c4 = 0; c4 < 48; ++c4) {
    float4 cv = crow[c4];
    const float* w0 = wgT + (size_t)(c4 * 4) * 1024 + chunk * 64;
    const float* w1 = w0 + 1024;
    const float* w2 = w1 + 1024;
    const float* w3 = w2 + 1024;
    #pragma unroll
    for (int o = 0; o < 64; ++o)
      acc[o] += cv.x*w0[o] + cv.y*w1[o] + cv.z*w2[o] + cv.w*w3[o];
  }
  const int lane = tid & 63;
  #pragma unroll
  for (int o = 0; o < 64; ++o) {
    int ch = chunk * 64 + o;
    float h = lrelu(acc[o] * sg[ch] + bg[ch]);
    #pragma unroll
    for (int m = 1; m < 64; m <<= 1) h = fmaxf(h, __shfl_xor(h, m));
    if (lane == 0) atomicMax(&gmax[b * 1024 + ch], fkey(h));
  }
}

// Output is FP32: [2][1024][8192] floats. (Also fully overwrites the featT
// scratch region that lived in d_out during the pipeline.)
__global__ __launch_bounds__(256) void bcast_kernel(const unsigned* __restrict__ gmax,
                                                    float* __restrict__ out)
{
  int t = blockIdx.x * 256 + threadIdx.x;   // each thread: 4 floats = 16B
  int bo = t >> 11;
  float v = funkey(gmax[bo]);
  float4 w; w.x = v; w.y = v; w.z = v; w.w = v;
  ((float4*)out)[t] = w;
}

// ---------------------------------------------------------------- launch
extern "C" void kernel_launch(void* const* d_in, const int* in_sizes, int n_in,
                              void* d_out, int out_size, void* d_ws, size_t ws_size,
                              hipStream_t stream)
{
  const float* points = (const float*)d_in[0];
  const float* w1a = (const float*)d_in[1];  const float* s1a = (const float*)d_in[2];  const float* b1a = (const float*)d_in[3];
  const float* w1b = (const float*)d_in[4];  const float* s1b = (const float*)d_in[5];  const float* b1b = (const float*)d_in[6];
  const float* w2a = (const float*)d_in[7];  const float* s2a = (const float*)d_in[8];  const float* b2a = (const float*)d_in[9];
  const float* w2b = (const float*)d_in[10]; const float* s2b = (const float*)d_in[11]; const float* b2b = (const float*)d_in[12];
  const float* w3a = (const float*)d_in[13]; const float* s3a = (const float*)d_in[14]; const float* b3a = (const float*)d_in[15];
  const float* wg  = (const float*)d_in[16]; const float* sg  = (const float*)d_in[17]; const float* bg  = (const float*)d_in[18];

  char* ws = (char*)d_ws;
  float*    cat   = (float*)(ws);                   // [2*8192][192]  12,582,912 B
  float*    xxbuf = (float*)(ws + 12582912);        // [2*8192]           65,536 B
  int*      idxb  = (int*)  (ws + 12648448);        // [2*8192][20]    1,310,720 B
  float*    wp1A  = (float*)(ws + 13959168);
  float*    wp1B  = (float*)(ws + 13961216);
  float*    wp2A  = (float*)(ws + 13977600);
  float*    wp2B  = (float*)(ws + 14010368);
  float*    wp3A  = (float*)(ws + 14026752);
  float*    wgT   = (float*)(ws + 14059520);
  unsigned* gmax  = (unsigned*)(ws + 14845952);
  const size_t WS_NEED = 14854144;
  if (ws_size < WS_NEED || n_in != 19) return;

  // featT scratch [2][64][8192] fp32 = 4 MB lives in d_out (67 MB), which is
  // fully overwritten by bcast_kernel at the end of every call.
  float* featT = (float*)d_out;

  prep_kernel<<<256, 256, 0, stream>>>(w1a, w1b, w2a, w2b, w3a, wg,
                                       wp1A, wp1B, wp2A, wp2B, wp3A, wgT);
  xx_points<<<64, 256, 0, stream>>>(points, xxbuf);
  knn3_kernel<<<4096, 512, 0, stream>>>(points, xxbuf, idxb);
  fused_conv<3, true, true><<<4096, 256, 0, stream>>>(
      points, 3, 0, idxb, (const float4*)wp1A, s1a, b1a,
      (const float4*)wp1B, s1b, b1b, cat, 0, xxbuf, featT);
  knn64_kernel<<<4096, 512, 0, stream>>>(featT, xxbuf, idxb);
  fused_conv<64, true, true><<<4096, 256, 0, stream>>>(
      cat, 192, 0, idxb, (const float4*)wp2A, s2a, b2a,
      (const float4*)wp2B, s2b, b2b, cat, 64, xxbuf, featT);
  knn64_kernel<<<4096, 512, 0, stream>>>(featT, xxbuf, idxb);
  fused_conv<64, false, false><<<4096, 256, 0, stream>>>(
      cat, 192, 64, idxb, (const float4*)wp3A, s3a, b3a,
      nullptr, nullptr, nullptr, cat, 128, nullptr, nullptr);
  init_gmax<<<8, 256, 0, stream>>>(gmax);
  final_kernel<<<1024, 256, 0, stream>>>(cat, wgT, sg, bg, gmax);
  bcast_kernel<<<16384, 256, 0, stream>>>(gmax, (float*)d_out);
}

// Round 10
// 2045.503 us; speedup vs baseline: 1.6286x; 1.6286x over previous
//
#include <hip/hip_runtime.h>
#include <hip/hip_bf16.h>

#define NPTS 8192
#define KNN  20
#define KC   4

__device__ __forceinline__ unsigned fkey(float f) {
  unsigned u = __float_as_uint(f);
  return (u & 0x80000000u) ? ~u : (u | 0x80000000u);
}
__device__ __forceinline__ float funkey(unsigned k) {
  return (k & 0x80000000u) ? __uint_as_float(k & 0x7fffffffu) : __uint_as_float(~k);
}
__device__ __forceinline__ float lrelu(float x) { return x >= 0.f ? x : 0.2f * x; }

// ---------------------------------------------------------------- prep weights
__global__ __launch_bounds__(256) void prep_kernel(
    const float* __restrict__ w1a, const float* __restrict__ w1b,
    const float* __restrict__ w2a, const float* __restrict__ w2b,
    const float* __restrict__ w3a, const float* __restrict__ wg,
    float* __restrict__ wp1A, float* __restrict__ wp1B,
    float* __restrict__ wp2A, float* __restrict__ wp2B,
    float* __restrict__ wp3A, float* __restrict__ wgT)
{
  const int t0 = blockIdx.x * blockDim.x + threadIdx.x;
  const int NT = gridDim.x * blockDim.x;
  for (int f = t0; f < 512; f += NT) {            // wp1A [2][64] f4, folded
    int i = f & 3, o = (f >> 2) & 63, c4 = f >> 8, c = c4 * 4 + i;
    float v = 0.f;
    if (c < 3)      v = w1a[o*12 + c]     + w1a[o*12 + c + 3];
    else if (c < 6) v = w1a[o*12 + c + 3] + w1a[o*12 + c + 6];
    wp1A[f] = v;
  }
  for (int f = t0; f < 4096; f += NT) {           // wp1B / wp2B [16][64] f4
    int i = f & 3, o = (f >> 2) & 63, c4 = f >> 8, c = c4 * 4 + i;
    wp1B[f] = w1b[o*64 + c];
    wp2B[f] = w2b[o*64 + c];
  }
  for (int f = t0; f < 8192; f += NT) {           // wp2A / wp3A [32][64] f4
    int i = f & 3, o = (f >> 2) & 63, c4 = f >> 8, c = c4 * 4 + i;
    wp2A[f] = w2a[o*128 + c];
    wp3A[f] = w3a[o*128 + c];
  }
  for (int f = t0; f < 192 * 1024; f += NT) {     // wgT [192][1024]
    int c = f >> 10, o = f & 1023;
    wgT[f] = wg[o*192 + c];
  }
}

// ---------------------------------------------------------------- point norms
__global__ __launch_bounds__(256) void xx_points(const float* __restrict__ pts,
                                                 float* __restrict__ xx)
{
  int t = blockIdx.x * 256 + threadIdx.x;
  if (t < 2 * NPTS) {
    const float* p = pts + (size_t)t * 3;
    xx[t] = p[0]*p[0] + p[1]*p[1] + p[2]*p[2];
  }
}

// ---------------------------------------------------------------- selection
// One-shot threshold top-20 (replaces 20 serial extraction rounds):
//  1. 64 chunk maxima (1/lane, 128-contiguous chunks, diagonal float4 reads)
//  2. bitonic-sort them desc -> That = 20th-largest chunk max.
//     That <= T20 (the 20 chunks with max >= That each contribute >= 1 elem),
//     so {v >= That} contains the exact top-20; expected size ~24.
//  3. ballot/popcount compaction of candidates into LDS (data-parallel).
//  4. bitonic-sort <=64 candidates desc on key (fkey(v)<<32)|~j — exactly
//     lax.top_k order (v desc, then j asc); lanes 0..19 write out.
//  5. M > 64 (pathological ties): exact slow fallback, per-wave.
__device__ __forceinline__ void bitonic64_desc_f(float& v, int lane) {
  #pragma unroll
  for (int k = 2; k <= 64; k <<= 1) {
    #pragma unroll
    for (int j = k >> 1; j >= 1; j >>= 1) {
      float o = __shfl_xor(v, j);
      bool take_max = (((lane & k) == 0) == ((lane & j) == 0));
      v = take_max ? fmaxf(v, o) : fminf(v, o);
    }
  }
}

__device__ __forceinline__ void bitonic64_desc_u64(unsigned long long& v, int lane) {
  #pragma unroll
  for (int k = 2; k <= 64; k <<= 1) {
    #pragma unroll
    for (int j = k >> 1; j >= 1; j >>= 1) {
      unsigned long long o = __shfl_xor(v, j);
      bool take_max = (((lane & k) == 0) == ((lane & j) == 0));
      unsigned long long hi = v > o ? v : o;
      unsigned long long lo = v > o ? o : v;
      v = take_max ? hi : lo;
    }
  }
}

__device__ void select20_fast(float* __restrict__ sdrow, int lane,
                              int* __restrict__ orow,
                              float* __restrict__ cv, int* __restrict__ cj)
{
  // 1. chunk maxima: chunk = lane, 128 contiguous elems, diagonal f4 reads
  float m = -INFINITY;
  const float4* rp = (const float4*)(sdrow + lane * 128);
  #pragma unroll
  for (int t = 0; t < 32; ++t) {
    float4 x = rp[(t + lane) & 31];
    m = fmaxf(m, fmaxf(fmaxf(x.x, x.y), fmaxf(x.z, x.w)));
  }
  // 2. threshold
  bitonic64_desc_f(m, lane);
  float That = __shfl(m, 19);

  // 3. compaction
  int base = 0;
  for (int i = 0; i < 128; ++i) {
    float v = sdrow[i * 64 + lane];
    bool p = (v >= That);
    unsigned long long mk = __ballot(p);
    if (p) {
      int pos = base + (int)__popcll(mk & ((1ull << lane) - 1ull));
      if (pos < 64) { cv[pos] = v; cj[pos] = i * 64 + lane; }
    }
    base += (int)__popcll(mk);
  }

  if (base <= 64) {
    // 4. exact sort of candidates
    unsigned long long key = 0ull;
    if (lane < base)
      key = (((unsigned long long)fkey(cv[lane])) << 32) | (unsigned)(~cj[lane]);
    bitonic64_desc_u64(key, lane);
    if (lane < KNN) orow[lane] = (int)((~(unsigned)key) & (NPTS - 1));
  } else {
    // 5. exact fallback: repeated full-row argmax with marking
    for (int kk = 0; kk < KNN; ++kk) {
      float bv = -INFINITY; int bj = NPTS;
      for (int i = 0; i < 128; ++i) {
        float v = sdrow[i * 64 + lane];
        if (v > bv) { bv = v; bj = i * 64 + lane; }
      }
      #pragma unroll
      for (int mm = 32; mm >= 1; mm >>= 1) {
        float ov = __shfl_xor(bv, mm); int oj = __shfl_xor(bj, mm);
        if (ov > bv || (ov == bv && oj < bj)) { bv = ov; bj = oj; }
      }
      if (lane == 0) orow[kk] = bj;
      sdrow[bj] = -INFINITY;            // all lanes, same addr/value
    }
  }
}

// ---------------------------------------------------------------- kNN on xyz
__global__ __launch_bounds__(512, 2) void knn3_kernel(
    const float* __restrict__ pts, const float* __restrict__ xx,
    int* __restrict__ idxout)
{
  __shared__ __align__(16) float sd[4][NPTS];          // 128 KB
  __shared__ float s_ctr[4][4];
  __shared__ float s_cv[4][64];
  __shared__ int   s_cj[4][64];
  const int tid = threadIdx.x;
  const int b   = blockIdx.x / (NPTS / 4);
  const int r0  = (blockIdx.x % (NPTS / 4)) * 4;
  const size_t rowbase = (size_t)b * NPTS;

  for (int i = tid; i < 12; i += 512)
    s_ctr[i / 3][i % 3] = pts[(rowbase + r0 + i / 3) * 3 + i % 3];
  __syncthreads();

  const float xr0 = xx[rowbase + r0 + 0], xr1 = xx[rowbase + r0 + 1];
  const float xr2 = xx[rowbase + r0 + 2], xr3 = xx[rowbase + r0 + 3];
  const float c00 = s_ctr[0][0], c01 = s_ctr[0][1], c02 = s_ctr[0][2];
  const float c10 = s_ctr[1][0], c11 = s_ctr[1][1], c12 = s_ctr[1][2];
  const float c20 = s_ctr[2][0], c21 = s_ctr[2][1], c22 = s_ctr[2][2];
  const float c30 = s_ctr[3][0], c31 = s_ctr[3][1], c32 = s_ctr[3][2];

  for (int j = tid; j < NPTS; j += 512) {
    const float* fj = pts + (rowbase + j) * 3;
    const float f0 = fj[0], f1 = fj[1], f2 = fj[2];
    const float xj = xx[rowbase + j];
    sd[0][j] = 2.f*(f0*c00 + f1*c01 + f2*c02) - xr0 - xj;
    sd[1][j] = 2.f*(f0*c10 + f1*c11 + f2*c12) - xr1 - xj;
    sd[2][j] = 2.f*(f0*c20 + f1*c21 + f2*c22) - xr2 - xj;
    sd[3][j] = 2.f*(f0*c30 + f1*c31 + f2*c32) - xr3 - xj;
  }
  __syncthreads();

  const int wid = tid >> 6, lane = tid & 63;
  if (wid < 4)
    select20_fast(sd[wid], lane, idxout + (rowbase + r0 + wid) * KNN,
                  s_cv[wid], s_cj[wid]);
}

// ---------------------------------------------------------------- kNN on 64-ch features
// featT channel-major [b][64][8192]: lane=point -> coalesced 1KB wave reads.
// 512 threads, launch_bounds(512,2) -> VGPR cap 256; unroll 4 bounds in-flight
// load regs (~124 VGPR, no spill). XCD swizzle pins each XCD to one batch's
// 2MB panel (L2-resident).
#define ACC4(A, C) \
  A.x += v0.x*C.x + v1.x*C.y + v2.x*C.z + v3.x*C.w; \
  A.y += v0.y*C.x + v1.y*C.y + v2.y*C.z + v3.y*C.w; \
  A.z += v0.z*C.x + v1.z*C.y + v2.z*C.z + v3.z*C.w; \
  A.w += v0.w*C.x + v1.w*C.y + v2.w*C.z + v3.w*C.w;

__global__ __launch_bounds__(512, 2) void knn64_kernel(
    const float* __restrict__ featT, const float* __restrict__ xx,
    int* __restrict__ idxout)
{
  __shared__ __align__(16) float sd[4][NPTS];          // 128 KB
  __shared__ __align__(16) float s_ctr[4][64];
  __shared__ float s_cv[4][64];
  __shared__ int   s_cj[4][64];
  const int tid = threadIdx.x;
  const int bid = blockIdx.x;
  const int b   = (bid & 7) >> 2;                      // XCD-batch swizzle
  const int r0  = (((bid >> 3) << 2) + (bid & 3)) * 4; // bijective rowgrp
  const size_t tb = (size_t)b * 64 * NPTS;
  const size_t rowbase = (size_t)b * NPTS;

  if (tid < 256)
    s_ctr[tid >> 6][tid & 63] = featT[tb + (size_t)(tid & 63) * NPTS + r0 + (tid >> 6)];
  __syncthreads();

  const int wid = tid >> 6, lane = tid & 63;
  const float xr0 = xx[rowbase + r0 + 0], xr1 = xx[rowbase + r0 + 1];
  const float xr2 = xx[rowbase + r0 + 2], xr3 = xx[rowbase + r0 + 3];
  const float4* ct0 = (const float4*)s_ctr[0];
  const float4* ct1 = (const float4*)s_ctr[1];
  const float4* ct2 = (const float4*)s_ctr[2];
  const float4* ct3 = (const float4*)s_ctr[3];

  #pragma unroll 1
  for (int ch = 0; ch < 4; ++ch) {
    const int jb = (wid << 10) + (ch << 8) + (lane << 2);   // 4 points per lane
    float4 a0 = {0.f,0.f,0.f,0.f}, a1 = a0, a2 = a0, a3 = a0;
    const float* fp0 = featT + tb + jb;
    #pragma unroll 4
    for (int c4 = 0; c4 < 16; ++c4) {
      const float* fp = fp0 + (size_t)(c4 * 4) * NPTS;
      float4 v0 = *(const float4*)(fp);
      float4 v1 = *(const float4*)(fp + NPTS);
      float4 v2 = *(const float4*)(fp + 2 * NPTS);
      float4 v3 = *(const float4*)(fp + 3 * NPTS);
      float4 c0 = ct0[c4], c1 = ct1[c4], c2 = ct2[c4], c3 = ct3[c4];
      ACC4(a0, c0); ACC4(a1, c1); ACC4(a2, c2); ACC4(a3, c3);
    }
    const float4 xv = *(const float4*)(xx + rowbase + jb);
    float4 s0, s1, s2, s3;
    s0.x = 2.f*a0.x - xr0 - xv.x; s0.y = 2.f*a0.y - xr0 - xv.y;
    s0.z = 2.f*a0.z - xr0 - xv.z; s0.w = 2.f*a0.w - xr0 - xv.w;
    s1.x = 2.f*a1.x - xr1 - xv.x; s1.y = 2.f*a1.y - xr1 - xv.y;
    s1.z = 2.f*a1.z - xr1 - xv.z; s1.w = 2.f*a1.w - xr1 - xv.w;
    s2.x = 2.f*a2.x - xr2 - xv.x; s2.y = 2.f*a2.y - xr2 - xv.y;
    s2.z = 2.f*a2.z - xr2 - xv.z; s2.w = 2.f*a2.w - xr2 - xv.w;
    s3.x = 2.f*a3.x - xr3 - xv.x; s3.y = 2.f*a3.y - xr3 - xv.y;
    s3.z = 2.f*a3.z - xr3 - xv.z; s3.w = 2.f*a3.w - xr3 - xv.w;
    *(float4*)&sd[0][jb] = s0;
    *(float4*)&sd[1][jb] = s1;
    *(float4*)&sd[2][jb] = s2;
    *(float4*)&sd[3][jb] = s3;
  }
  __syncthreads();

  if (wid < 4)
    select20_fast(sd[wid], lane, idxout + (rowbase + r0 + wid) * KNN,
                  s_cv[wid], s_cj[wid]);
}

// ---------------------------------------------------------------- fused EdgeConv
// Block = 4 points x 64 channels (wave = one point). WAUX: also writes xx
// (feature norms for next kNN) and the channel-major featT panel.
template<int D, bool HASB, bool WAUX>
__global__ __launch_bounds__(256) void fused_conv(
    const float* __restrict__ feat, int fstride, int foff,
    const int* __restrict__ idx,
    const float4* __restrict__ wAp, const float* __restrict__ sa, const float* __restrict__ ba,
    const float4* __restrict__ wBp, const float* __restrict__ sb, const float* __restrict__ bb,
    float* __restrict__ outbuf, int ooff, float* __restrict__ xxout,
    float* __restrict__ featT)
{
  constexpr int CHA  = (D == 64) ? 32 : 2;   // float4 chunks of 2D (padded)
  constexpr int CHA4 = CHA * 4;
  __shared__ float4 s_wA[CHA * 64];
  __shared__ float4 s_wB[HASB ? 16 * 64 : 1];
  __shared__ __align__(16) float4 s_g[4 * KC * CHA];
  __shared__ __align__(16) float  s_h1[HASB ? 4 * KC * 64 : 4];
  __shared__ float s_ctr[4][(D > 4) ? D : 4];
  __shared__ float s_sa[64], s_ba[64], s_sb[64], s_bb[64];

  const int tid = threadIdx.x;
  const int p = tid >> 6, o = tid & 63;
  const int b  = blockIdx.x / (NPTS / 4);
  const int p0 = (blockIdx.x % (NPTS / 4)) * 4;
  const size_t rowbase = (size_t)b * NPTS;

  for (int i = tid; i < CHA * 64; i += 256) s_wA[i] = wAp[i];
  if (HASB) for (int i = tid; i < 16 * 64; i += 256) s_wB[i] = wBp[i];
  if (tid < 64) {
    s_sa[tid] = sa[tid]; s_ba[tid] = ba[tid];
    if (HASB) { s_sb[tid] = sb[tid]; s_bb[tid] = bb[tid]; }
  }
  for (int i = tid; i < 4 * D; i += 256)
    s_ctr[i / D][i % D] = feat[(rowbase + p0 + (i / D)) * fstride + foff + (i % D)];
  __syncthreads();

  float* s_gf = (float*)s_g;
  float hmax = -INFINITY;
  for (int kc = 0; kc < KNN / KC; ++kc) {
    for (int s = tid; s < 4 * KC * CHA4; s += 256) {
      int pp = s / (KC * CHA4);
      int rr = s - pp * (KC * CHA4);
      int kk = rr / CHA4;
      int c  = rr - kk * CHA4;
      int nb = idx[(rowbase + p0 + pp) * KNN + kc * KC + kk];
      float v;
      if (D == 64) {
        v = (c < 64) ? (feat[(rowbase + nb) * fstride + foff + c] - s_ctr[pp][c])
                     : s_ctr[pp][c - 64];
      } else {
        if (c < 3)      v = feat[(rowbase + nb) * 3 + c] - s_ctr[pp][c];
        else if (c < 6) v = s_ctr[pp][c - 3];
        else            v = 0.f;
      }
      s_gf[s] = v;
    }
    __syncthreads();

    float acc[KC];
    #pragma unroll
    for (int kk = 0; kk < KC; ++kk) acc[kk] = 0.f;
    for (int c4 = 0; c4 < CHA; ++c4) {
      float4 w = s_wA[c4 * 64 + o];
      #pragma unroll
      for (int kk = 0; kk < KC; ++kk) {
        float4 g = s_g[(p * KC + kk) * CHA + c4];
        acc[kk] += w.x*g.x + w.y*g.y + w.z*g.z + w.w*g.w;
      }
    }
    if (HASB) {
      #pragma unroll
      for (int kk = 0; kk < KC; ++kk)
        s_h1[(p * KC + kk) * 64 + o] = lrelu(acc[kk] * s_sa[o] + s_ba[o]);
      __syncthreads();
      float acc2[KC];
      #pragma unroll
      for (int kk = 0; kk < KC; ++kk) acc2[kk] = 0.f;
      const float4* s_h14 = (const float4*)s_h1;
      for (int c4 = 0; c4 < 16; ++c4) {
        float4 w = s_wB[c4 * 64 + o];
        #pragma unroll
        for (int kk = 0; kk < KC; ++kk) {
          float4 h = s_h14[(p * KC + kk) * 16 + c4];
          acc2[kk] += w.x*h.x + w.y*h.y + w.z*h.z + w.w*h.w;
        }
      }
      #pragma unroll
      for (int kk = 0; kk < KC; ++kk)
        hmax = fmaxf(hmax, lrelu(acc2[kk] * s_sb[o] + s_bb[o]));
      __syncthreads();
    } else {
      #pragma unroll
      for (int kk = 0; kk < KC; ++kk)
        hmax = fmaxf(hmax, lrelu(acc[kk] * s_sa[o] + s_ba[o]));
      __syncthreads();
    }
  }
  outbuf[(rowbase + p0 + p) * 192 + ooff + o] = hmax;
  if (WAUX) {
    featT[(size_t)b * 64 * NPTS + (size_t)o * NPTS + (p0 + p)] = hmax;
    float ss = hmax * hmax;
    #pragma unroll
    for (int m = 1; m < 64; m <<= 1) ss += __shfl_xor(ss, m);
    if (o == 0) xxout[rowbase + p0 + p] = ss;
  }
}

// ---------------------------------------------------------------- final 192->1024
__global__ __launch_bounds__(256) void init_gmax(unsigned* __restrict__ g)
{
  int t = blockIdx.x * 256 + threadIdx.x;
  if (t < 2048) g[t] = fkey(-1e30f);
}

__global__ __launch_bounds__(256) void final_kernel(
    const float* __restrict__ cat, const float* __restrict__ wgT,
    const float* __restrict__ sg, const float* __restrict__ bg,
    unsigned* __restrict__ gmax)
{
  const int tid = threadIdx.x;
  const int chunk = blockIdx.x & 15;
  const int grp   = blockIdx.x >> 4;
  const int pt = grp * 256 + tid;
  const int b  = pt >> 13;
  const float4* crow = (const float4*)(cat + (size_t)pt * 192);
  float acc[64];
  #pragma unroll
  for (int o = 0; o < 64; ++o) acc[o] = 0.f;
  for (int c4 = 0; c4 < 48; ++c4) {
    float4 cv = crow[c4];
    const float* w0 = wgT + (size_t)(c4 * 4) * 1024 + chunk * 64;
    const float* w1 = w0 + 1024;
    const float* w2 = w1 + 1024;
    const float* w3 = w2 + 1024;
    #pragma unroll
    for (int o = 0; o < 64; ++o)
      acc[o] += cv.x*w0[o] + cv.y*w1[o] + cv.z*w2[o] + cv.w*w3[o];
  }
  const int lane = tid & 63;
  #pragma unroll
  for (int o = 0; o < 64; ++o) {
    int ch = chunk * 64 + o;
    float h = lrelu(acc[o] * sg[ch] + bg[ch]);
    #pragma unroll
    for (int m = 1; m < 64; m <<= 1) h = fmaxf(h, __shfl_xor(h, m));
    if (lane == 0) atomicMax(&gmax[b * 1024 + ch], fkey(h));
  }
}

// Output is FP32: [2][1024][8192] floats. (Also fully overwrites the featT
// scratch region that lived in d_out during the pipeline.)
__global__ __launch_bounds__(256) void bcast_kernel(const unsigned* __restrict__ gmax,
                                                    float* __restrict__ out)
{
  int t = blockIdx.x * 256 + threadIdx.x;   // each thread: 4 floats = 16B
  int bo = t >> 11;
  float v = funkey(gmax[bo]);
  float4 w; w.x = v; w.y = v; w.z = v; w.w = v;
  ((float4*)out)[t] = w;
}

// ---------------------------------------------------------------- launch
extern "C" void kernel_launch(void* const* d_in, const int* in_sizes, int n_in,
                              void* d_out, int out_size, void* d_ws, size_t ws_size,
                              hipStream_t stream)
{
  const float* points = (const float*)d_in[0];
  const float* w1a = (const float*)d_in[1];  const float* s1a = (const float*)d_in[2];  const float* b1a = (const float*)d_in[3];
  const float* w1b = (const float*)d_in[4];  const float* s1b = (const float*)d_in[5];  const float* b1b = (const float*)d_in[6];
  const float* w2a = (const float*)d_in[7];  const float* s2a = (const float*)d_in[8];  const float* b2a = (const float*)d_in[9];
  const float* w2b = (const float*)d_in[10]; const float* s2b = (const float*)d_in[11]; const float* b2b = (const float*)d_in[12];
  const float* w3a = (const float*)d_in[13]; const float* s3a = (const float*)d_in[14]; const float* b3a = (const float*)d_in[15];
  const float* wg  = (const float*)d_in[16]; const float* sg  = (const float*)d_in[17]; const float* bg  = (const float*)d_in[18];

  char* ws = (char*)d_ws;
  float*    cat   = (float*)(ws);                   // [2*8192][192]  12,582,912 B
  float*    xxbuf = (float*)(ws + 12582912);        // [2*8192]           65,536 B
  int*      idxb  = (int*)  (ws + 12648448);        // [2*8192][20]    1,310,720 B
  float*    wp1A  = (float*)(ws + 13959168);
  float*    wp1B  = (float*)(ws + 13961216);
  float*    wp2A  = (float*)(ws + 13977600);
  float*    wp2B  = (float*)(ws + 14010368);
  float*    wp3A  = (float*)(ws + 14026752);
  float*    wgT   = (float*)(ws + 14059520);
  unsigned* gmax  = (unsigned*)(ws + 14845952);
  const size_t WS_NEED = 14854144;
  if (ws_size < WS_NEED || n_in != 19) return;

  // featT scratch [2][64][8192] fp32 = 4 MB lives in d_out (67 MB), which is
  // fully overwritten by bcast_kernel at the end of every call.
  float* featT = (float*)d_out;

  prep_kernel<<<256, 256, 0, stream>>>(w1a, w1b, w2a, w2b, w3a, wg,
                                       wp1A, wp1B, wp2A, wp2B, wp3A, wgT);
  xx_points<<<64, 256, 0, stream>>>(points, xxbuf);
  knn3_kernel<<<4096, 512, 0, stream>>>(points, xxbuf, idxb);
  fused_conv<3, true, true><<<4096, 256, 0, stream>>>(
      points, 3, 0, idxb, (const float4*)wp1A, s1a, b1a,
      (const float4*)wp1B, s1b, b1b, cat, 0, xxbuf, featT);
  knn64_kernel<<<4096, 512, 0, stream>>>(featT, xxbuf, idxb);
  fused_conv<64, true, true><<<4096, 256, 0, stream>>>(
      cat, 192, 0, idxb, (const float4*)wp2A, s2a, b2a,
      (const float4*)wp2B, s2b, b2b, cat, 64, xxbuf, featT);
  knn64_kernel<<<4096, 512, 0, stream>>>(featT, xxbuf, idxb);
  fused_conv<64, false, false><<<4096, 256, 0, stream>>>(
      cat, 192, 64, idxb, (const float4*)wp3A, s3a, b3a,
      nullptr, nullptr, nullptr, cat, 128, nullptr, nullptr);
  init_gmax<<<8, 256, 0, stream>>>(gmax);
  final_kernel<<<1024, 256, 0, stream>>>(cat, wgT, sg, bg, gmax);
  bcast_kernel<<<16384, 256, 0, stream>>>(gmax, (float*)d_out);
}

// Round 11
// 1845.140 us; speedup vs baseline: 1.8054x; 1.1086x over previous
//
#include <hip/hip_runtime.h>
#include <hip/hip_bf16.h>

#define NPTS 8192
#define KNN  20
#define KC   4

__device__ __forceinline__ unsigned fkey(float f) {
  unsigned u = __float_as_uint(f);
  return (u & 0x80000000u) ? ~u : (u | 0x80000000u);
}
__device__ __forceinline__ float funkey(unsigned k) {
  return (k & 0x80000000u) ? __uint_as_float(k & 0x7fffffffu) : __uint_as_float(~k);
}
__device__ __forceinline__ float lrelu(float x) { return x >= 0.f ? x : 0.2f * x; }

// ---------------------------------------------------------------- prep weights
__global__ __launch_bounds__(256) void prep_kernel(
    const float* __restrict__ w1a, const float* __restrict__ w1b,
    const float* __restrict__ w2a, const float* __restrict__ w2b,
    const float* __restrict__ w3a, const float* __restrict__ wg,
    float* __restrict__ wp1A, float* __restrict__ wp1B,
    float* __restrict__ wp2A, float* __restrict__ wp2B,
    float* __restrict__ wp3A, float* __restrict__ wgT)
{
  const int t0 = blockIdx.x * blockDim.x + threadIdx.x;
  const int NT = gridDim.x * blockDim.x;
  for (int f = t0; f < 512; f += NT) {            // wp1A [2][64] f4, folded
    int i = f & 3, o = (f >> 2) & 63, c4 = f >> 8, c = c4 * 4 + i;
    float v = 0.f;
    if (c < 3)      v = w1a[o*12 + c]     + w1a[o*12 + c + 3];
    else if (c < 6) v = w1a[o*12 + c + 3] + w1a[o*12 + c + 6];
    wp1A[f] = v;
  }
  for (int f = t0; f < 4096; f += NT) {           // wp1B / wp2B [16][64] f4
    int i = f & 3, o = (f >> 2) & 63, c4 = f >> 8, c = c4 * 4 + i;
    wp1B[f] = w1b[o*64 + c];
    wp2B[f] = w2b[o*64 + c];
  }
  for (int f = t0; f < 8192; f += NT) {           // wp2A / wp3A [32][64] f4
    int i = f & 3, o = (f >> 2) & 63, c4 = f >> 8, c = c4 * 4 + i;
    wp2A[f] = w2a[o*128 + c];
    wp3A[f] = w3a[o*128 + c];
  }
  for (int f = t0; f < 192 * 1024; f += NT) {     // wgT [192][1024]
    int c = f >> 10, o = f & 1023;
    wgT[f] = wg[o*192 + c];
  }
}

// ---------------------------------------------------------------- point norms
__global__ __launch_bounds__(256) void xx_points(const float* __restrict__ pts,
                                                 float* __restrict__ xx)
{
  int t = blockIdx.x * 256 + threadIdx.x;
  if (t < 2 * NPTS) {
    const float* p = pts + (size_t)t * 3;
    xx[t] = p[0]*p[0] + p[1]*p[1] + p[2]*p[2];
  }
}

// ---------------------------------------------------------------- selection
__device__ __forceinline__ void bitonic64_desc_f(float& v, int lane) {
  #pragma unroll
  for (int k = 2; k <= 64; k <<= 1) {
    #pragma unroll
    for (int j = k >> 1; j >= 1; j >>= 1) {
      float o = __shfl_xor(v, j);
      bool take_max = (((lane & k) == 0) == ((lane & j) == 0));
      v = take_max ? fmaxf(v, o) : fminf(v, o);
    }
  }
}

__device__ __forceinline__ void bitonic64_desc_u64(unsigned long long& v, int lane) {
  #pragma unroll
  for (int k = 2; k <= 64; k <<= 1) {
    #pragma unroll
    for (int j = k >> 1; j >= 1; j >>= 1) {
      unsigned long long o = __shfl_xor(v, j);
      bool take_max = (((lane & k) == 0) == ((lane & j) == 0));
      unsigned long long hi = v > o ? v : o;
      unsigned long long lo = v > o ? o : v;
      v = take_max ? hi : lo;
    }
  }
}

// Exact top-20 of one 4096-elem HALF (sd row live in LDS):
//  64 chunk maxima -> bitonic -> That = 20th-largest (<= true T20 of half,
//  since >=20 chunks contribute >=1 elem each) -> ballot compaction of
//  {v >= That} (expected ~24, cap 64) -> bitonic on (fkey(v)<<32)|~j =
//  exact lax.top_k order. Overflow (>64, pathological ties): serial exact
//  fallback on the live half. Outputs (value, GLOBAL j) for the merge.
__device__ void sel20_half(float* __restrict__ sdh, int half, int lane,
                           float* __restrict__ hv, int* __restrict__ hj,
                           float* __restrict__ cv, int* __restrict__ cj)
{
  float m = -INFINITY;
  const float4* rp = (const float4*)(sdh + lane * 64);
  #pragma unroll
  for (int t = 0; t < 16; ++t) {
    float4 x = rp[(t + lane) & 15];
    m = fmaxf(m, fmaxf(fmaxf(x.x, x.y), fmaxf(x.z, x.w)));
  }
  bitonic64_desc_f(m, lane);
  float That = __shfl(m, 19);

  int base = 0;
  for (int i = 0; i < 64; ++i) {
    float v = sdh[i * 64 + lane];
    bool p = (v >= That);
    unsigned long long mk = __ballot(p);
    if (p) {
      int pos = base + (int)__popcll(mk & ((1ull << lane) - 1ull));
      if (pos < 64) { cv[pos] = v; cj[pos] = i * 64 + lane; }
    }
    base += (int)__popcll(mk);
  }

  if (base <= 64) {
    unsigned long long key = 0ull;
    if (lane < base)
      key = (((unsigned long long)fkey(cv[lane])) << 32) | (unsigned)(~cj[lane]);
    bitonic64_desc_u64(key, lane);
    if (lane < KNN) {
      hv[lane] = funkey((unsigned)(key >> 32));
      hj[lane] = (half << 12) + (int)((~(unsigned)key) & 4095u);
    }
  } else {
    for (int kk = 0; kk < KNN; ++kk) {
      float bv = -INFINITY; int bj = 4096;
      for (int i = 0; i < 64; ++i) {
        float v = sdh[i * 64 + lane];
        if (v > bv) { bv = v; bj = i * 64 + lane; }
      }
      #pragma unroll
      for (int mm = 32; mm >= 1; mm >>= 1) {
        float ov = __shfl_xor(bv, mm); int oj = __shfl_xor(bj, mm);
        if (ov > bv || (ov == bv && oj < bj)) { bv = ov; bj = oj; }
      }
      if (lane == 0) { hv[kk] = bv; hj[kk] = (half << 12) + bj; }
      sdh[bj] = -INFINITY;            // all lanes, same addr/value
    }
  }
}

// Merge 2x20 exact half-results -> global top-20 (superset property:
// top-20(full) is contained in top-20(half0) U top-20(half1)).
__device__ __forceinline__ void merge_halves(const float* __restrict__ hv,
                                             const int* __restrict__ hj,
                                             int lane, int* __restrict__ orow)
{
  unsigned long long key = 0ull;
  if (lane < 2 * KNN)
    key = (((unsigned long long)fkey(hv[lane])) << 32) | (unsigned)(~hj[lane]);
  bitonic64_desc_u64(key, lane);
  if (lane < KNN) orow[lane] = (int)((~(unsigned)key) & (NPTS - 1));
}

// ---------------------------------------------------------------- kNN on xyz
// Two j-phases of 4096 -> sd is 64KB -> 2 blocks/CU (4 waves/SIMD).
__global__ __launch_bounds__(512, 4) void knn3_kernel(
    const float* __restrict__ pts, const float* __restrict__ xx,
    int* __restrict__ idxout)
{
  __shared__ __align__(16) float sd[4][4096];          // 64 KB
  __shared__ float s_ctr[4][4];
  __shared__ float s_hv[4][2 * KNN];
  __shared__ int   s_hj[4][2 * KNN];
  __shared__ float s_cv[4][64];
  __shared__ int   s_cj[4][64];
  const int tid = threadIdx.x;
  const int b   = blockIdx.x / (NPTS / 4);
  const int r0  = (blockIdx.x % (NPTS / 4)) * 4;
  const size_t rowbase = (size_t)b * NPTS;

  for (int i = tid; i < 12; i += 512)
    s_ctr[i / 3][i % 3] = pts[(rowbase + r0 + i / 3) * 3 + i % 3];
  __syncthreads();

  const float xr0 = xx[rowbase + r0 + 0], xr1 = xx[rowbase + r0 + 1];
  const float xr2 = xx[rowbase + r0 + 2], xr3 = xx[rowbase + r0 + 3];
  const float c00 = s_ctr[0][0], c01 = s_ctr[0][1], c02 = s_ctr[0][2];
  const float c10 = s_ctr[1][0], c11 = s_ctr[1][1], c12 = s_ctr[1][2];
  const float c20 = s_ctr[2][0], c21 = s_ctr[2][1], c22 = s_ctr[2][2];
  const float c30 = s_ctr[3][0], c31 = s_ctr[3][1], c32 = s_ctr[3][2];
  const int wid = tid >> 6, lane = tid & 63;

  #pragma unroll 1
  for (int h = 0; h < 2; ++h) {
    for (int jl = tid; jl < 4096; jl += 512) {
      const int jg = (h << 12) + jl;
      const float* fj = pts + (rowbase + jg) * 3;
      const float f0 = fj[0], f1 = fj[1], f2 = fj[2];
      const float xj = xx[rowbase + jg];
      sd[0][jl] = 2.f*(f0*c00 + f1*c01 + f2*c02) - xr0 - xj;
      sd[1][jl] = 2.f*(f0*c10 + f1*c11 + f2*c12) - xr1 - xj;
      sd[2][jl] = 2.f*(f0*c20 + f1*c21 + f2*c22) - xr2 - xj;
      sd[3][jl] = 2.f*(f0*c30 + f1*c31 + f2*c32) - xr3 - xj;
    }
    __syncthreads();
    if (wid < 4)
      sel20_half(sd[wid], h, lane, &s_hv[wid][h * KNN], &s_hj[wid][h * KNN],
                 s_cv[wid], s_cj[wid]);
    __syncthreads();
  }
  if (wid < 4)
    merge_halves(s_hv[wid], s_hj[wid], lane, idxout + (rowbase + r0 + wid) * KNN);
}

// ---------------------------------------------------------------- kNN on 64-ch features
// featT channel-major [b][64][8192]: lane=point -> coalesced 1KB wave reads.
// Two j-phases of 4096 -> 64KB sd -> 2 blocks/CU. launch_bounds(512,4) caps
// VGPR at 128 (dist body needs ~124; R6/R7 spill lesson). unroll 4 bounds
// in-flight load regs. XCD swizzle pins each XCD to one batch's 2MB panel.
#define ACC4(A, C) \
  A.x += v0.x*C.x + v1.x*C.y + v2.x*C.z + v3.x*C.w; \
  A.y += v0.y*C.x + v1.y*C.y + v2.y*C.z + v3.y*C.w; \
  A.z += v0.z*C.x + v1.z*C.y + v2.z*C.z + v3.z*C.w; \
  A.w += v0.w*C.x + v1.w*C.y + v2.w*C.z + v3.w*C.w;

__global__ __launch_bounds__(512, 4) void knn64_kernel(
    const float* __restrict__ featT, const float* __restrict__ xx,
    int* __restrict__ idxout)
{
  __shared__ __align__(16) float sd[4][4096];          // 64 KB
  __shared__ __align__(16) float s_ctr[4][64];
  __shared__ float s_hv[4][2 * KNN];
  __shared__ int   s_hj[4][2 * KNN];
  __shared__ float s_cv[4][64];
  __shared__ int   s_cj[4][64];
  const int tid = threadIdx.x;
  const int bid = blockIdx.x;
  const int b   = (bid & 7) >> 2;                      // XCD-batch swizzle
  const int r0  = (((bid >> 3) << 2) + (bid & 3)) * 4; // bijective rowgrp
  const size_t tb = (size_t)b * 64 * NPTS;
  const size_t rowbase = (size_t)b * NPTS;

  if (tid < 256)
    s_ctr[tid >> 6][tid & 63] = featT[tb + (size_t)(tid & 63) * NPTS + r0 + (tid >> 6)];
  __syncthreads();

  const int wid = tid >> 6, lane = tid & 63;
  const float xr0 = xx[rowbase + r0 + 0], xr1 = xx[rowbase + r0 + 1];
  const float xr2 = xx[rowbase + r0 + 2], xr3 = xx[rowbase + r0 + 3];
  const float4* ct0 = (const float4*)s_ctr[0];
  const float4* ct1 = (const float4*)s_ctr[1];
  const float4* ct2 = (const float4*)s_ctr[2];
  const float4* ct3 = (const float4*)s_ctr[3];

  #pragma unroll 1
  for (int h = 0; h < 2; ++h) {
    #pragma unroll 1
    for (int ch = 0; ch < 2; ++ch) {
      const int jl = (wid << 9) + (ch << 8) + (lane << 2);   // local in half
      const int jg = (h << 12) + jl;                          // global j
      float4 a0 = {0.f,0.f,0.f,0.f}, a1 = a0, a2 = a0, a3 = a0;
      const float* fp0 = featT + tb + jg;
      #pragma unroll 4
      for (int c4 = 0; c4 < 16; ++c4) {
        const float* fp = fp0 + (size_t)(c4 * 4) * NPTS;
        float4 v0 = *(const float4*)(fp);
        float4 v1 = *(const float4*)(fp + NPTS);
        float4 v2 = *(const float4*)(fp + 2 * NPTS);
        float4 v3 = *(const float4*)(fp + 3 * NPTS);
        float4 c0 = ct0[c4], c1 = ct1[c4], c2 = ct2[c4], c3 = ct3[c4];
        ACC4(a0, c0); ACC4(a1, c1); ACC4(a2, c2); ACC4(a3, c3);
      }
      const float4 xv = *(const float4*)(xx + rowbase + jg);
      float4 s0, s1, s2, s3;
      s0.x = 2.f*a0.x - xr0 - xv.x; s0.y = 2.f*a0.y - xr0 - xv.y;
      s0.z = 2.f*a0.z - xr0 - xv.z; s0.w = 2.f*a0.w - xr0 - xv.w;
      s1.x = 2.f*a1.x - xr1 - xv.x; s1.y = 2.f*a1.y - xr1 - xv.y;
      s1.z = 2.f*a1.z - xr1 - xv.z; s1.w = 2.f*a1.w - xr1 - xv.w;
      s2.x = 2.f*a2.x - xr2 - xv.x; s2.y = 2.f*a2.y - xr2 - xv.y;
      s2.z = 2.f*a2.z - xr2 - xv.z; s2.w = 2.f*a2.w - xr2 - xv.w;
      s3.x = 2.f*a3.x - xr3 - xv.x; s3.y = 2.f*a3.y - xr3 - xv.y;
      s3.z = 2.f*a3.z - xr3 - xv.z; s3.w = 2.f*a3.w - xr3 - xv.w;
      *(float4*)&sd[0][jl] = s0;
      *(float4*)&sd[1][jl] = s1;
      *(float4*)&sd[2][jl] = s2;
      *(float4*)&sd[3][jl] = s3;
    }
    __syncthreads();
    if (wid < 4)
      sel20_half(sd[wid], h, lane, &s_hv[wid][h * KNN], &s_hj[wid][h * KNN],
                 s_cv[wid], s_cj[wid]);
    __syncthreads();
  }
  if (wid < 4)
    merge_halves(s_hv[wid], s_hj[wid], lane, idxout + (rowbase + r0 + wid) * KNN);
}

// ---------------------------------------------------------------- fused EdgeConv
// Block = 4 points x 64 channels (wave = one point). WAUX: also writes xx
// (feature norms for next kNN) and the channel-major featT panel.
template<int D, bool HASB, bool WAUX>
__global__ __launch_bounds__(256) void fused_conv(
    const float* __restrict__ feat, int fstride, int foff,
    const int* __restrict__ idx,
    const float4* __restrict__ wAp, const float* __restrict__ sa, const float* __restrict__ ba,
    const float4* __restrict__ wBp, const float* __restrict__ sb, const float* __restrict__ bb,
    float* __restrict__ outbuf, int ooff, float* __restrict__ xxout,
    float* __restrict__ featT)
{
  constexpr int CHA  = (D == 64) ? 32 : 2;   // float4 chunks of 2D (padded)
  constexpr int CHA4 = CHA * 4;
  __shared__ float4 s_wA[CHA * 64];
  __shared__ float4 s_wB[HASB ? 16 * 64 : 1];
  __shared__ __align__(16) float4 s_g[4 * KC * CHA];
  __shared__ __align__(16) float  s_h1[HASB ? 4 * KC * 64 : 4];
  __shared__ float s_ctr[4][(D > 4) ? D : 4];
  __shared__ float s_sa[64], s_ba[64], s_sb[64], s_bb[64];

  const int tid = threadIdx.x;
  const int p = tid >> 6, o = tid & 63;
  const int b  = blockIdx.x / (NPTS / 4);
  const int p0 = (blockIdx.x % (NPTS / 4)) * 4;
  const size_t rowbase = (size_t)b * NPTS;

  for (int i = tid; i < CHA * 64; i += 256) s_wA[i] = wAp[i];
  if (HASB) for (int i = tid; i < 16 * 64; i += 256) s_wB[i] = wBp[i];
  if (tid < 64) {
    s_sa[tid] = sa[tid]; s_ba[tid] = ba[tid];
    if (HASB) { s_sb[tid] = sb[tid]; s_bb[tid] = bb[tid]; }
  }
  for (int i = tid; i < 4 * D; i += 256)
    s_ctr[i / D][i % D] = feat[(rowbase + p0 + (i / D)) * fstride + foff + (i % D)];
  __syncthreads();

  float* s_gf = (float*)s_g;
  float hmax = -INFINITY;
  for (int kc = 0; kc < KNN / KC; ++kc) {
    for (int s = tid; s < 4 * KC * CHA4; s += 256) {
      int pp = s / (KC * CHA4);
      int rr = s - pp * (KC * CHA4);
      int kk = rr / CHA4;
      int c  = rr - kk * CHA4;
      int nb = idx[(rowbase + p0 + pp) * KNN + kc * KC + kk];
      float v;
      if (D == 64) {
        v = (c < 64) ? (feat[(rowbase + nb) * fstride + foff + c] - s_ctr[pp][c])
                     : s_ctr[pp][c - 64];
      } else {
        if (c < 3)      v = feat[(rowbase + nb) * 3 + c] - s_ctr[pp][c];
        else if (c < 6) v = s_ctr[pp][c - 3];
        else            v = 0.f;
      }
      s_gf[s] = v;
    }
    __syncthreads();

    float acc[KC];
    #pragma unroll
    for (int kk = 0; kk < KC; ++kk) acc[kk] = 0.f;
    for (int c4 = 0; c4 < CHA; ++c4) {
      float4 w = s_wA[c4 * 64 + o];
      #pragma unroll
      for (int kk = 0; kk < KC; ++kk) {
        float4 g = s_g[(p * KC + kk) * CHA + c4];
        acc[kk] += w.x*g.x + w.y*g.y + w.z*g.z + w.w*g.w;
      }
    }
    if (HASB) {
      #pragma unroll
      for (int kk = 0; kk < KC; ++kk)
        s_h1[(p * KC + kk) * 64 + o] = lrelu(acc[kk] * s_sa[o] + s_ba[o]);
      __syncthreads();
      float acc2[KC];
      #pragma unroll
      for (int kk = 0; kk < KC; ++kk) acc2[kk] = 0.f;
      const float4* s_h14 = (const float4*)s_h1;
      for (int c4 = 0; c4 < 16; ++c4) {
        float4 w = s_wB[c4 * 64 + o];
        #pragma unroll
        for (int kk = 0; kk < KC; ++kk) {
          float4 h = s_h14[(p * KC + kk) * 16 + c4];
          acc2[kk] += w.x*h.x + w.y*h.y + w.z*h.z + w.w*h.w;
        }
      }
      #pragma unroll
      for (int kk = 0; kk < KC; ++kk)
        hmax = fmaxf(hmax, lrelu(acc2[kk] * s_sb[o] + s_bb[o]));
      __syncthreads();
    } else {
      #pragma unroll
      for (int kk = 0; kk < KC; ++kk)
        hmax = fmaxf(hmax, lrelu(acc[kk] * s_sa[o] + s_ba[o]));
      __syncthreads();
    }
  }
  outbuf[(rowbase + p0 + p) * 192 + ooff + o] = hmax;
  if (WAUX) {
    featT[(size_t)b * 64 * NPTS + (size_t)o * NPTS + (p0 + p)] = hmax;
    float ss = hmax * hmax;
    #pragma unroll
    for (int m = 1; m < 64; m <<= 1) ss += __shfl_xor(ss, m);
    if (o == 0) xxout[rowbase + p0 + p] = ss;
  }
}

// ---------------------------------------------------------------- final 192->1024
__global__ __launch_bounds__(256) void init_gmax(unsigned* __restrict__ g)
{
  int t = blockIdx.x * 256 + threadIdx.x;
  if (t < 2048) g[t] = fkey(-1e30f);
}

__global__ __launch_bounds__(256) void final_kernel(
    const float* __restrict__ cat, const float* __restrict__ wgT,
    const float* __restrict__ sg, const float* __restrict__ bg,
    unsigned* __restrict__ gmax)
{
  const int tid = threadIdx.x;
  const int chunk = blockIdx.x & 15;
  const int grp   = blockIdx.x >> 4;
  const int pt = grp * 256 + tid;
  const int b  = pt >> 13;
  const float4* crow = (const float4*)(cat + (size_t)pt * 192);
  float acc[64];
  #pragma unroll
  for (int o = 0; o < 64; ++o) acc[o] = 0.f;
  for (int c4 = 0; c4 < 48; ++c4) {
    float4 cv = crow[c4];
    const float* w0 = wgT + (size_t)(c4 * 4) * 1024 + chunk * 64;
    const float* w1 = w0 + 1024;
    const float* w2 = w1 + 1024;
    const float* w3 = w2 + 1024;
    #pragma unroll
    for (int o = 0; o < 64; ++o)
      acc[o] += cv.x*w0[o] + cv.y*w1[o] + cv.z*w2[o] + cv.w*w3[o];
  }
  const int lane = tid & 63;
  #pragma unroll
  for (int o = 0; o < 64; ++o) {
    int ch = chunk * 64 + o;
    float h = lrelu(acc[o] * sg[ch] + bg[ch]);
    #pragma unroll
    for (int m = 1; m < 64; m <<= 1) h = fmaxf(h, __shfl_xor(h, m));
    if (lane == 0) atomicMax(&gmax[b * 1024 + ch], fkey(h));
  }
}

// Output is FP32: [2][1024][8192] floats. (Also fully overwrites the featT
// scratch region that lived in d_out during the pipeline.)
__global__ __launch_bounds__(256) void bcast_kernel(const unsigned* __restrict__ gmax,
                                                    float* __restrict__ out)
{
  int t = blockIdx.x * 256 + threadIdx.x;   // each thread: 4 floats = 16B
  int bo = t >> 11;
  float v = funkey(gmax[bo]);
  float4 w; w.x = v; w.y = v; w.z = v; w.w = v;
  ((float4*)out)[t] = w;
}

// ---------------------------------------------------------------- launch
extern "C" void kernel_launch(void* const* d_in, const int* in_sizes, int n_in,
                              void* d_out, int out_size, void* d_ws, size_t ws_size,
                              hipStream_t stream)
{
  const float* points = (const float*)d_in[0];
  const float* w1a = (const float*)d_in[1];  const float* s1a = (const float*)d_in[2];  const float* b1a = (const float*)d_in[3];
  const float* w1b = (const float*)d_in[4];  const float* s1b = (const float*)d_in[5];  const float* b1b = (const float*)d_in[6];
  const float* w2a = (const float*)d_in[7];  const float* s2a = (const float*)d_in[8];  const float* b2a = (const float*)d_in[9];
  const float* w2b = (const float*)d_in[10]; const float* s2b = (const float*)d_in[11]; const float* b2b = (const float*)d_in[12];
  const float* w3a = (const float*)d_in[13]; const float* s3a = (const float*)d_in[14]; const float* b3a = (const float*)d_in[15];
  const float* wg  = (const float*)d_in[16]; const float* sg  = (const float*)d_in[17]; const float* bg  = (const float*)d_in[18];

  char* ws = (char*)d_ws;
  float*    cat   = (float*)(ws);                   // [2*8192][192]  12,582,912 B
  float*    xxbuf = (float*)(ws + 12582912);        // [2*8192]           65,536 B
  int*      idxb  = (int*)  (ws + 12648448);        // [2*8192][20]    1,310,720 B
  float*    wp1A  = (float*)(ws + 13959168);
  float*    wp1B  = (float*)(ws + 13961216);
  float*    wp2A  = (float*)(ws + 13977600);
  float*    wp2B  = (float*)(ws + 14010368);
  float*    wp3A  = (float*)(ws + 14026752);
  float*    wgT   = (float*)(ws + 14059520);
  unsigned* gmax  = (unsigned*)(ws + 14845952);
  const size_t WS_NEED = 14854144;
  if (ws_size < WS_NEED || n_in != 19) return;

  // featT scratch [2][64][8192] fp32 = 4 MB lives in d_out (67 MB), which is
  // fully overwritten by bcast_kernel at the end of every call.
  float* featT = (float*)d_out;

  prep_kernel<<<256, 256, 0, stream>>>(w1a, w1b, w2a, w2b, w3a, wg,
                                       wp1A, wp1B, wp2A, wp2B, wp3A, wgT);
  xx_points<<<64, 256, 0, stream>>>(points, xxbuf);
  knn3_kernel<<<4096, 512, 0, stream>>>(points, xxbuf, idxb);
  fused_conv<3, true, true><<<4096, 256, 0, stream>>>(
      points, 3, 0, idxb, (const float4*)wp1A, s1a, b1a,
      (const float4*)wp1B, s1b, b1b, cat, 0, xxbuf, featT);
  knn64_kernel<<<4096, 512, 0, stream>>>(featT, xxbuf, idxb);
  fused_conv<64, true, true><<<4096, 256, 0, stream>>>(
      cat, 192, 0, idxb, (const float4*)wp2A, s2a, b2a,
      (const float4*)wp2B, s2b, b2b, cat, 64, xxbuf, featT);
  knn64_kernel<<<4096, 512, 0, stream>>>(featT, xxbuf, idxb);
  fused_conv<64, false, false><<<4096, 256, 0, stream>>>(
      cat, 192, 64, idxb, (const float4*)wp3A, s3a, b3a,
      nullptr, nullptr, nullptr, cat, 128, nullptr, nullptr);
  init_gmax<<<8, 256, 0, stream>>>(gmax);
  final_kernel<<<1024, 256, 0, stream>>>(cat, wgT, sg, bg, gmax);
  bcast_kernel<<<16384, 256, 0, stream>>>(gmax, (float*)d_out);
}

// Round 12
// 1780.060 us; speedup vs baseline: 1.8714x; 1.0366x over previous
//
#include <hip/hip_runtime.h>
#include <hip/hip_bf16.h>

#define NPTS 8192
#define KNN  20
#define KC   4

__device__ __forceinline__ unsigned fkey(float f) {
  unsigned u = __float_as_uint(f);
  return (u & 0x80000000u) ? ~u : (u | 0x80000000u);
}
__device__ __forceinline__ float funkey(unsigned k) {
  return (k & 0x80000000u) ? __uint_as_float(k & 0x7fffffffu) : __uint_as_float(~k);
}
__device__ __forceinline__ float lrelu(float x) { return x >= 0.f ? x : 0.2f * x; }

// ---------------------------------------------------------------- prep weights
__global__ __launch_bounds__(256) void prep_kernel(
    const float* __restrict__ w1a, const float* __restrict__ w1b,
    const float* __restrict__ w2a, const float* __restrict__ w2b,
    const float* __restrict__ w3a, const float* __restrict__ wg,
    float* __restrict__ wp1A, float* __restrict__ wp1B,
    float* __restrict__ wp2A, float* __restrict__ wp2B,
    float* __restrict__ wp3A, float* __restrict__ wgT)
{
  const int t0 = blockIdx.x * blockDim.x + threadIdx.x;
  const int NT = gridDim.x * blockDim.x;
  for (int f = t0; f < 512; f += NT) {            // wp1A [2][64] f4, folded
    int i = f & 3, o = (f >> 2) & 63, c4 = f >> 8, c = c4 * 4 + i;
    float v = 0.f;
    if (c < 3)      v = w1a[o*12 + c]     + w1a[o*12 + c + 3];
    else if (c < 6) v = w1a[o*12 + c + 3] + w1a[o*12 + c + 6];
    wp1A[f] = v;
  }
  for (int f = t0; f < 4096; f += NT) {           // wp1B / wp2B [16][64] f4
    int i = f & 3, o = (f >> 2) & 63, c4 = f >> 8, c = c4 * 4 + i;
    wp1B[f] = w1b[o*64 + c];
    wp2B[f] = w2b[o*64 + c];
  }
  for (int f = t0; f < 8192; f += NT) {           // wp2A / wp3A [32][64] f4
    int i = f & 3, o = (f >> 2) & 63, c4 = f >> 8, c = c4 * 4 + i;
    wp2A[f] = w2a[o*128 + c];
    wp3A[f] = w3a[o*128 + c];
  }
  for (int f = t0; f < 192 * 1024; f += NT) {     // wgT [192][1024]
    int c = f >> 10, o = f & 1023;
    wgT[f] = wg[o*192 + c];
  }
}

// ---------------------------------------------------------------- point norms
__global__ __launch_bounds__(256) void xx_points(const float* __restrict__ pts,
                                                 float* __restrict__ xx)
{
  int t = blockIdx.x * 256 + threadIdx.x;
  if (t < 2 * NPTS) {
    const float* p = pts + (size_t)t * 3;
    xx[t] = p[0]*p[0] + p[1]*p[1] + p[2]*p[2];
  }
}

// ---------------------------------------------------------------- selection
__device__ __forceinline__ void bitonic64_desc_f(float& v, int lane) {
  #pragma unroll
  for (int k = 2; k <= 64; k <<= 1) {
    #pragma unroll
    for (int j = k >> 1; j >= 1; j >>= 1) {
      float o = __shfl_xor(v, j);
      bool take_max = (((lane & k) == 0) == ((lane & j) == 0));
      v = take_max ? fmaxf(v, o) : fminf(v, o);
    }
  }
}

__device__ __forceinline__ void bitonic64_desc_u64(unsigned long long& v, int lane) {
  #pragma unroll
  for (int k = 2; k <= 64; k <<= 1) {
    #pragma unroll
    for (int j = k >> 1; j >= 1; j >>= 1) {
      unsigned long long o = __shfl_xor(v, j);
      bool take_max = (((lane & k) == 0) == ((lane & j) == 0));
      unsigned long long hi = v > o ? v : o;
      unsigned long long lo = v > o ? o : v;
      v = take_max ? hi : lo;
    }
  }
}

// Exact top-20 of one 4096-elem HALF (R10/R11-proven; used by knn3):
__device__ void sel20_half(float* __restrict__ sdh, int half, int lane,
                           float* __restrict__ hv, int* __restrict__ hj,
                           float* __restrict__ cv, int* __restrict__ cj)
{
  float m = -INFINITY;
  const float4* rp = (const float4*)(sdh + lane * 64);
  #pragma unroll
  for (int t = 0; t < 16; ++t) {
    float4 x = rp[(t + lane) & 15];
    m = fmaxf(m, fmaxf(fmaxf(x.x, x.y), fmaxf(x.z, x.w)));
  }
  bitonic64_desc_f(m, lane);
  float That = __shfl(m, 19);

  int base = 0;
  for (int i = 0; i < 64; ++i) {
    float v = sdh[i * 64 + lane];
    bool p = (v >= That);
    unsigned long long mk = __ballot(p);
    if (p) {
      int pos = base + (int)__popcll(mk & ((1ull << lane) - 1ull));
      if (pos < 64) { cv[pos] = v; cj[pos] = i * 64 + lane; }
    }
    base += (int)__popcll(mk);
  }

  if (base <= 64) {
    unsigned long long key = 0ull;
    if (lane < base)
      key = (((unsigned long long)fkey(cv[lane])) << 32) | (unsigned)(~cj[lane]);
    bitonic64_desc_u64(key, lane);
    if (lane < KNN) {
      hv[lane] = funkey((unsigned)(key >> 32));
      hj[lane] = (half << 12) + (int)((~(unsigned)key) & 4095u);
    }
  } else {
    for (int kk = 0; kk < KNN; ++kk) {
      float bv = -INFINITY; int bj = 4096;
      for (int i = 0; i < 64; ++i) {
        float v = sdh[i * 64 + lane];
        if (v > bv) { bv = v; bj = i * 64 + lane; }
      }
      #pragma unroll
      for (int mm = 32; mm >= 1; mm >>= 1) {
        float ov = __shfl_xor(bv, mm); int oj = __shfl_xor(bj, mm);
        if (ov > bv || (ov == bv && oj < bj)) { bv = ov; bj = oj; }
      }
      if (lane == 0) { hv[kk] = bv; hj[kk] = (half << 12) + bj; }
      sdh[bj] = -INFINITY;            // all lanes, same addr/value
    }
  }
}

__device__ __forceinline__ void merge_halves(const float* __restrict__ hv,
                                             const int* __restrict__ hj,
                                             int lane, int* __restrict__ orow)
{
  unsigned long long key = 0ull;
  if (lane < 2 * KNN)
    key = (((unsigned long long)fkey(hv[lane])) << 32) | (unsigned)(~hj[lane]);
  bitonic64_desc_u64(key, lane);
  if (lane < KNN) orow[lane] = (int)((~(unsigned)key) & (NPTS - 1));
}

// Exact top-20 of one 2048-elem QUARTER; returns sorted u64 keys on lanes
// 0..19 (key = (fkey(v)<<32)|~jglobal). Chunks are stride-interleaved (chunk
// = lane, elems {i*64+lane}) -> all LDS reads conflict-free. Threshold =
// 20th-largest chunk max (<= true T20 since >=20 chunks contribute >=1 elem
// each). Expected candidates ~24, cap 64; exact serial fallback otherwise.
__device__ unsigned long long sel20_quarter(float* __restrict__ sdq, int jbase,
                                            int lane, float* __restrict__ cv,
                                            int* __restrict__ cj)
{
  float m = -INFINITY;
  #pragma unroll 8
  for (int i = 0; i < 32; ++i) m = fmaxf(m, sdq[i * 64 + lane]);
  bitonic64_desc_f(m, lane);
  float That = __shfl(m, 19);

  int base = 0;
  for (int i = 0; i < 32; ++i) {
    float v = sdq[i * 64 + lane];
    bool p = (v >= That);
    unsigned long long mk = __ballot(p);
    if (p) {
      int pos = base + (int)__popcll(mk & ((1ull << lane) - 1ull));
      if (pos < 64) { cv[pos] = v; cj[pos] = jbase + i * 64 + lane; }
    }
    base += (int)__popcll(mk);
  }

  unsigned long long key = 0ull;
  if (base <= 64) {
    if (lane < base)
      key = (((unsigned long long)fkey(cv[lane])) << 32) | (unsigned)(~cj[lane]);
    bitonic64_desc_u64(key, lane);
  } else {
    for (int kk = 0; kk < KNN; ++kk) {
      float bv = -INFINITY; int bj = 2048;
      for (int i = 0; i < 32; ++i) {
        float v = sdq[i * 64 + lane];
        if (v > bv) { bv = v; bj = i * 64 + lane; }
      }
      #pragma unroll
      for (int mm = 32; mm >= 1; mm >>= 1) {
        float ov = __shfl_xor(bv, mm); int oj = __shfl_xor(bj, mm);
        if (ov > bv || (ov == bv && oj < bj)) { bv = ov; bj = oj; }
      }
      if (lane == kk)
        key = (((unsigned long long)fkey(bv)) << 32) | (unsigned)(~(jbase + bj));
      sdq[bj] = -INFINITY;            // all lanes, same addr/value
    }
  }
  return key;
}

// ---------------------------------------------------------------- kNN on xyz
// (unchanged from R11: two 4096-halves, 2 blocks/CU)
__global__ __launch_bounds__(512, 4) void knn3_kernel(
    const float* __restrict__ pts, const float* __restrict__ xx,
    int* __restrict__ idxout)
{
  __shared__ __align__(16) float sd[4][4096];          // 64 KB
  __shared__ float s_ctr[4][4];
  __shared__ float s_hv[4][2 * KNN];
  __shared__ int   s_hj[4][2 * KNN];
  __shared__ float s_cv[4][64];
  __shared__ int   s_cj[4][64];
  const int tid = threadIdx.x;
  const int b   = blockIdx.x / (NPTS / 4);
  const int r0  = (blockIdx.x % (NPTS / 4)) * 4;
  const size_t rowbase = (size_t)b * NPTS;

  for (int i = tid; i < 12; i += 512)
    s_ctr[i / 3][i % 3] = pts[(rowbase + r0 + i / 3) * 3 + i % 3];
  __syncthreads();

  const float xr0 = xx[rowbase + r0 + 0], xr1 = xx[rowbase + r0 + 1];
  const float xr2 = xx[rowbase + r0 + 2], xr3 = xx[rowbase + r0 + 3];
  const float c00 = s_ctr[0][0], c01 = s_ctr[0][1], c02 = s_ctr[0][2];
  const float c10 = s_ctr[1][0], c11 = s_ctr[1][1], c12 = s_ctr[1][2];
  const float c20 = s_ctr[2][0], c21 = s_ctr[2][1], c22 = s_ctr[2][2];
  const float c30 = s_ctr[3][0], c31 = s_ctr[3][1], c32 = s_ctr[3][2];
  const int wid = tid >> 6, lane = tid & 63;

  #pragma unroll 1
  for (int h = 0; h < 2; ++h) {
    for (int jl = tid; jl < 4096; jl += 512) {
      const int jg = (h << 12) + jl;
      const float* fj = pts + (rowbase + jg) * 3;
      const float f0 = fj[0], f1 = fj[1], f2 = fj[2];
      const float xj = xx[rowbase + jg];
      sd[0][jl] = 2.f*(f0*c00 + f1*c01 + f2*c02) - xr0 - xj;
      sd[1][jl] = 2.f*(f0*c10 + f1*c11 + f2*c12) - xr1 - xj;
      sd[2][jl] = 2.f*(f0*c20 + f1*c21 + f2*c22) - xr2 - xj;
      sd[3][jl] = 2.f*(f0*c30 + f1*c31 + f2*c32) - xr3 - xj;
    }
    __syncthreads();
    if (wid < 4)
      sel20_half(sd[wid], h, lane, &s_hv[wid][h * KNN], &s_hj[wid][h * KNN],
                 s_cv[wid], s_cj[wid]);
    __syncthreads();
  }
  if (wid < 4)
    merge_halves(s_hv[wid], s_hj[wid], lane, idxout + (rowbase + r0 + wid) * KNN);
}

// ---------------------------------------------------------------- kNN on 64-ch features
// 8 query rows/block (halves the L2 panel traffic: 2048 blocks x 2MB = 4GB),
// 4 j-phases of 2048 -> sd[8][2048] = 64KB -> still 2 blocks/CU, 4 waves/SIMD.
// Running top-20 kept in REGISTERS as sorted u64 keys; per-phase merge =
// shfl-shift + bitonic64. unroll 2 bounds in-flight load regs (8-row acc
// needs 32 VGPRs; spill tripwire = WRITE_SIZE).
#define ACC4(A, C) \
  A.x += v0.x*C.x + v1.x*C.y + v2.x*C.z + v3.x*C.w; \
  A.y += v0.y*C.x + v1.y*C.y + v2.y*C.z + v3.y*C.w; \
  A.z += v0.z*C.x + v1.z*C.y + v2.z*C.z + v3.z*C.w; \
  A.w += v0.w*C.x + v1.w*C.y + v2.w*C.z + v3.w*C.w;

__global__ __launch_bounds__(512, 4) void knn64_kernel(
    const float* __restrict__ featT, const float* __restrict__ xx,
    int* __restrict__ idxout)
{
  __shared__ __align__(16) float sd[8][2048];          // 64 KB
  __shared__ __align__(16) float s_ctr[8][64];         // 2 KB
  __shared__ float s_cv[8][64];
  __shared__ int   s_cj[8][64];
  const int tid = threadIdx.x;
  const int bid = blockIdx.x;
  const int b   = (bid & 7) >> 2;                      // XCD-batch swizzle
  const int r0  = (((bid >> 3) << 2) + (bid & 3)) * 8; // bijective rowgrp
  const size_t tb = (size_t)b * 64 * NPTS;
  const size_t rowbase = (size_t)b * NPTS;

  s_ctr[tid >> 6][tid & 63] = featT[tb + (size_t)(tid & 63) * NPTS + r0 + (tid >> 6)];
  __syncthreads();

  const int wid = tid >> 6, lane = tid & 63;
  float xr[8];
  #pragma unroll
  for (int r = 0; r < 8; ++r) xr[r] = xx[rowbase + r0 + r];
  const float4* ct0 = (const float4*)s_ctr[0];
  const float4* ct1 = (const float4*)s_ctr[1];
  const float4* ct2 = (const float4*)s_ctr[2];
  const float4* ct3 = (const float4*)s_ctr[3];
  const float4* ct4 = (const float4*)s_ctr[4];
  const float4* ct5 = (const float4*)s_ctr[5];
  const float4* ct6 = (const float4*)s_ctr[6];
  const float4* ct7 = (const float4*)s_ctr[7];

  unsigned long long runkey = 0ull;

  #pragma unroll 1
  for (int h = 0; h < 4; ++h) {
    const int jl = (wid << 8) + (lane << 2);            // 4 points per lane
    const int jg = (h << 11) + jl;
    float4 a0 = {0.f,0.f,0.f,0.f}, a1 = a0, a2 = a0, a3 = a0;
    float4 a4 = a0, a5 = a0, a6 = a0, a7 = a0;
    const float* fp0 = featT + tb + jg;
    #pragma unroll 2
    for (int c4 = 0; c4 < 16; ++c4) {
      const float* fp = fp0 + (size_t)(c4 * 4) * NPTS;
      float4 v0 = *(const float4*)(fp);
      float4 v1 = *(const float4*)(fp + NPTS);
      float4 v2 = *(const float4*)(fp + 2 * NPTS);
      float4 v3 = *(const float4*)(fp + 3 * NPTS);
      float4 c;
      c = ct0[c4]; ACC4(a0, c);
      c = ct1[c4]; ACC4(a1, c);
      c = ct2[c4]; ACC4(a2, c);
      c = ct3[c4]; ACC4(a3, c);
      c = ct4[c4]; ACC4(a4, c);
      c = ct5[c4]; ACC4(a5, c);
      c = ct6[c4]; ACC4(a6, c);
      c = ct7[c4]; ACC4(a7, c);
    }
    const float4 xv = *(const float4*)(xx + rowbase + jg);
    float4 s;
    #define STORE_ROW(A, R) \
      s.x = 2.f*A.x - xr[R] - xv.x; s.y = 2.f*A.y - xr[R] - xv.y; \
      s.z = 2.f*A.z - xr[R] - xv.z; s.w = 2.f*A.w - xr[R] - xv.w; \
      *(float4*)&sd[R][jl] = s;
    STORE_ROW(a0, 0); STORE_ROW(a1, 1); STORE_ROW(a2, 2); STORE_ROW(a3, 3);
    STORE_ROW(a4, 4); STORE_ROW(a5, 5); STORE_ROW(a6, 6); STORE_ROW(a7, 7);
    #undef STORE_ROW
    __syncthreads();

    // selection: wave = row; result keys on lanes 0..19, then register merge
    unsigned long long pk = sel20_quarter(sd[wid], h << 11, lane,
                                          s_cv[wid], s_cj[wid]);
    unsigned long long nk = __shfl(pk, lane - 20);
    unsigned long long mkey = (lane < 20) ? runkey
                            : ((lane < 40) ? nk : 0ull);
    bitonic64_desc_u64(mkey, lane);
    runkey = mkey;
    __syncthreads();
  }
  if (lane < KNN)
    idxout[(rowbase + r0 + wid) * KNN + lane] =
        (int)((~(unsigned)runkey) & (NPTS - 1));
}

// ---------------------------------------------------------------- fused EdgeConv
template<int D, bool HASB, bool WAUX>
__global__ __launch_bounds__(256) void fused_conv(
    const float* __restrict__ feat, int fstride, int foff,
    const int* __restrict__ idx,
    const float4* __restrict__ wAp, const float* __restrict__ sa, const float* __restrict__ ba,
    const float4* __restrict__ wBp, const float* __restrict__ sb, const float* __restrict__ bb,
    float* __restrict__ outbuf, int ooff, float* __restrict__ xxout,
    float* __restrict__ featT)
{
  constexpr int CHA  = (D == 64) ? 32 : 2;   // float4 chunks of 2D (padded)
  constexpr int CHA4 = CHA * 4;
  __shared__ float4 s_wA[CHA * 64];
  __shared__ float4 s_wB[HASB ? 16 * 64 : 1];
  __shared__ __align__(16) float4 s_g[4 * KC * CHA];
  __shared__ __align__(16) float  s_h1[HASB ? 4 * KC * 64 : 4];
  __shared__ float s_ctr[4][(D > 4) ? D : 4];
  __shared__ float s_sa[64], s_ba[64], s_sb[64], s_bb[64];

  const int tid = threadIdx.x;
  const int p = tid >> 6, o = tid & 63;
  const int b  = blockIdx.x / (NPTS / 4);
  const int p0 = (blockIdx.x % (NPTS / 4)) * 4;
  const size_t rowbase = (size_t)b * NPTS;

  for (int i = tid; i < CHA * 64; i += 256) s_wA[i] = wAp[i];
  if (HASB) for (int i = tid; i < 16 * 64; i += 256) s_wB[i] = wBp[i];
  if (tid < 64) {
    s_sa[tid] = sa[tid]; s_ba[tid] = ba[tid];
    if (HASB) { s_sb[tid] = sb[tid]; s_bb[tid] = bb[tid]; }
  }
  for (int i = tid; i < 4 * D; i += 256)
    s_ctr[i / D][i % D] = feat[(rowbase + p0 + (i / D)) * fstride + foff + (i % D)];
  __syncthreads();

  float* s_gf = (float*)s_g;
  float hmax = -INFINITY;
  for (int kc = 0; kc < KNN / KC; ++kc) {
    for (int s = tid; s < 4 * KC * CHA4; s += 256) {
      int pp = s / (KC * CHA4);
      int rr = s - pp * (KC * CHA4);
      int kk = rr / CHA4;
      int c  = rr - kk * CHA4;
      int nb = idx[(rowbase + p0 + pp) * KNN + kc * KC + kk];
      float v;
      if (D == 64) {
        v = (c < 64) ? (feat[(rowbase + nb) * fstride + foff + c] - s_ctr[pp][c])
                     : s_ctr[pp][c - 64];
      } else {
        if (c < 3)      v = feat[(rowbase + nb) * 3 + c] - s_ctr[pp][c];
        else if (c < 6) v = s_ctr[pp][c - 3];
        else            v = 0.f;
      }
      s_gf[s] = v;
    }
    __syncthreads();

    float acc[KC];
    #pragma unroll
    for (int kk = 0; kk < KC; ++kk) acc[kk] = 0.f;
    for (int c4 = 0; c4 < CHA; ++c4) {
      float4 w = s_wA[c4 * 64 + o];
      #pragma unroll
      for (int kk = 0; kk < KC; ++kk) {
        float4 g = s_g[(p * KC + kk) * CHA + c4];
        acc[kk] += w.x*g.x + w.y*g.y + w.z*g.z + w.w*g.w;
      }
    }
    if (HASB) {
      #pragma unroll
      for (int kk = 0; kk < KC; ++kk)
        s_h1[(p * KC + kk) * 64 + o] = lrelu(acc[kk] * s_sa[o] + s_ba[o]);
      __syncthreads();
      float acc2[KC];
      #pragma unroll
      for (int kk = 0; kk < KC; ++kk) acc2[kk] = 0.f;
      const float4* s_h14 = (const float4*)s_h1;
      for (int c4 = 0; c4 < 16; ++c4) {
        float4 w = s_wB[c4 * 64 + o];
        #pragma unroll
        for (int kk = 0; kk < KC; ++kk) {
          float4 h = s_h14[(p * KC + kk) * 16 + c4];
          acc2[kk] += w.x*h.x + w.y*h.y + w.z*h.z + w.w*h.w;
        }
      }
      #pragma unroll
      for (int kk = 0; kk < KC; ++kk)
        hmax = fmaxf(hmax, lrelu(acc2[kk] * s_sb[o] + s_bb[o]));
      __syncthreads();
    } else {
      #pragma unroll
      for (int kk = 0; kk < KC; ++kk)
        hmax = fmaxf(hmax, lrelu(acc[kk] * s_sa[o] + s_ba[o]));
      __syncthreads();
    }
  }
  outbuf[(rowbase + p0 + p) * 192 + ooff + o] = hmax;
  if (WAUX) {
    featT[(size_t)b * 64 * NPTS + (size_t)o * NPTS + (p0 + p)] = hmax;
    float ss = hmax * hmax;
    #pragma unroll
    for (int m = 1; m < 64; m <<= 1) ss += __shfl_xor(ss, m);
    if (o == 0) xxout[rowbase + p0 + p] = ss;
  }
}

// ---------------------------------------------------------------- final 192->1024
__global__ __launch_bounds__(256) void init_gmax(unsigned* __restrict__ g)
{
  int t = blockIdx.x * 256 + threadIdx.x;
  if (t < 2048) g[t] = fkey(-1e30f);
}

__global__ __launch_bounds__(256) void final_kernel(
    const float* __restrict__ cat, const float* __restrict__ wgT,
    const float* __restrict__ sg, const float* __restrict__ bg,
    unsigned* __restrict__ gmax)
{
  const int tid = threadIdx.x;
  const int chunk = blockIdx.x & 15;
  const int grp   = blockIdx.x >> 4;
  const int pt = grp * 256 + tid;
  const int b  = pt >> 13;
  const float4* crow = (const float4*)(cat + (size_t)pt * 192);
  float acc[64];
  #pragma unroll
  for (int o = 0; o < 64; ++o) acc[o] = 0.f;
  for (int c4 = 0; c4 < 48; ++c4) {
    float4 cv = crow[c4];
    const float* w0 = wgT + (size_t)(c4 * 4) * 1024 + chunk * 64;
    const float* w1 = w0 + 1024;
    const float* w2 = w1 + 1024;
    const float* w3 = w2 + 1024;
    #pragma unroll
    for (int o = 0; o < 64; ++o)
      acc[o] += cv.x*w0[o] + cv.y*w1[o] + cv.z*w2[o] + cv.w*w3[o];
  }
  const int lane = tid & 63;
  #pragma unroll
  for (int o = 0; o < 64; ++o) {
    int ch = chunk * 64 + o;
    float h = lrelu(acc[o] * sg[ch] + bg[ch]);
    #pragma unroll
    for (int m = 1; m < 64; m <<= 1) h = fmaxf(h, __shfl_xor(h, m));
    if (lane == 0) atomicMax(&gmax[b * 1024 + ch], fkey(h));
  }
}

// Output is FP32: [2][1024][8192] floats. (Also fully overwrites the featT
// scratch region that lived in d_out during the pipeline.)
__global__ __launch_bounds__(256) void bcast_kernel(const unsigned* __restrict__ gmax,
                                                    float* __restrict__ out)
{
  int t = blockIdx.x * 256 + threadIdx.x;   // each thread: 4 floats = 16B
  int bo = t >> 11;
  float v = funkey(gmax[bo]);
  float4 w; w.x = v; w.y = v; w.z = v; w.w = v;
  ((float4*)out)[t] = w;
}

// ---------------------------------------------------------------- launch
extern "C" void kernel_launch(void* const* d_in, const int* in_sizes, int n_in,
                              void* d_out, int out_size, void* d_ws, size_t ws_size,
                              hipStream_t stream)
{
  const float* points = (const float*)d_in[0];
  const float* w1a = (const float*)d_in[1];  const float* s1a = (const float*)d_in[2];  const float* b1a = (const float*)d_in[3];
  const float* w1b = (const float*)d_in[4];  const float* s1b = (const float*)d_in[5];  const float* b1b = (const float*)d_in[6];
  const float* w2a = (const float*)d_in[7];  const float* s2a = (const float*)d_in[8];  const float* b2a = (const float*)d_in[9];
  const float* w2b = (const float*)d_in[10]; const float* s2b = (const float*)d_in[11]; const float* b2b = (const float*)d_in[12];
  const float* w3a = (const float*)d_in[13]; const float* s3a = (const float*)d_in[14]; const float* b3a = (const float*)d_in[15];
  const float* wg  = (const float*)d_in[16]; const float* sg  = (const float*)d_in[17]; const float* bg  = (const float*)d_in[18];

  char* ws = (char*)d_ws;
  float*    cat   = (float*)(ws);                   // [2*8192][192]  12,582,912 B
  float*    xxbuf = (float*)(ws + 12582912);        // [2*8192]           65,536 B
  int*      idxb  = (int*)  (ws + 12648448);        // [2*8192][20]    1,310,720 B
  float*    wp1A  = (float*)(ws + 13959168);
  float*    wp1B  = (float*)(ws + 13961216);
  float*    wp2A  = (float*)(ws + 13977600);
  float*    wp2B  = (float*)(ws + 14010368);
  float*    wp3A  = (float*)(ws + 14026752);
  float*    wgT   = (float*)(ws + 14059520);
  unsigned* gmax  = (unsigned*)(ws + 14845952);
  const size_t WS_NEED = 14854144;
  if (ws_size < WS_NEED || n_in != 19) return;

  // featT scratch [2][64][8192] fp32 = 4 MB lives in d_out (67 MB), which is
  // fully overwritten by bcast_kernel at the end of every call.
  float* featT = (float*)d_out;

  prep_kernel<<<256, 256, 0, stream>>>(w1a, w1b, w2a, w2b, w3a, wg,
                                       wp1A, wp1B, wp2A, wp2B, wp3A, wgT);
  xx_points<<<64, 256, 0, stream>>>(points, xxbuf);
  knn3_kernel<<<4096, 512, 0, stream>>>(points, xxbuf, idxb);
  fused_conv<3, true, true><<<4096, 256, 0, stream>>>(
      points, 3, 0, idxb, (const float4*)wp1A, s1a, b1a,
      (const float4*)wp1B, s1b, b1b, cat, 0, xxbuf, featT);
  knn64_kernel<<<2048, 512, 0, stream>>>(featT, xxbuf, idxb);
  fused_conv<64, true, true><<<4096, 256, 0, stream>>>(
      cat, 192, 0, idxb, (const float4*)wp2A, s2a, b2a,
      (const float4*)wp2B, s2b, b2b, cat, 64, xxbuf, featT);
  knn64_kernel<<<2048, 512, 0, stream>>>(featT, xxbuf, idxb);
  fused_conv<64, false, false><<<4096, 256, 0, stream>>>(
      cat, 192, 64, idxb, (const float4*)wp3A, s3a, b3a,
      nullptr, nullptr, nullptr, cat, 128, nullptr, nullptr);
  init_gmax<<<8, 256, 0, stream>>>(gmax);
  final_kernel<<<1024, 256, 0, stream>>>(cat, wgT, sg, bg, gmax);
  bcast_kernel<<<16384, 256, 0, stream>>>(gmax, (float*)d_out);
}

// Round 13
// 1678.873 us; speedup vs baseline: 1.9842x; 1.0603x over previous
//
#include <hip/hip_runtime.h>
#include <hip/hip_bf16.h>

#define NPTS 8192
#define KNN  20
#define KC   4

__device__ __forceinline__ unsigned fkey(float f) {
  unsigned u = __float_as_uint(f);
  return (u & 0x80000000u) ? ~u : (u | 0x80000000u);
}
__device__ __forceinline__ float funkey(unsigned k) {
  return (k & 0x80000000u) ? __uint_as_float(k & 0x7fffffffu) : __uint_as_float(~k);
}
__device__ __forceinline__ float lrelu(float x) { return x >= 0.f ? x : 0.2f * x; }

// ---------------------------------------------------------------- prep weights
__global__ __launch_bounds__(256) void prep_kernel(
    const float* __restrict__ w1a, const float* __restrict__ w1b,
    const float* __restrict__ w2a, const float* __restrict__ w2b,
    const float* __restrict__ w3a, const float* __restrict__ wg,
    float* __restrict__ wp1A, float* __restrict__ wp1B,
    float* __restrict__ wp2A, float* __restrict__ wp2B,
    float* __restrict__ wp3A, float* __restrict__ wgT)
{
  const int t0 = blockIdx.x * blockDim.x + threadIdx.x;
  const int NT = gridDim.x * blockDim.x;
  for (int f = t0; f < 512; f += NT) {            // wp1A [2][64] f4, folded
    int i = f & 3, o = (f >> 2) & 63, c4 = f >> 8, c = c4 * 4 + i;
    float v = 0.f;
    if (c < 3)      v = w1a[o*12 + c]     + w1a[o*12 + c + 3];
    else if (c < 6) v = w1a[o*12 + c + 3] + w1a[o*12 + c + 6];
    wp1A[f] = v;
  }
  for (int f = t0; f < 4096; f += NT) {           // wp1B / wp2B [16][64] f4
    int i = f & 3, o = (f >> 2) & 63, c4 = f >> 8, c = c4 * 4 + i;
    wp1B[f] = w1b[o*64 + c];
    wp2B[f] = w2b[o*64 + c];
  }
  for (int f = t0; f < 8192; f += NT) {           // wp2A / wp3A [32][64] f4
    int i = f & 3, o = (f >> 2) & 63, c4 = f >> 8, c = c4 * 4 + i;
    wp2A[f] = w2a[o*128 + c];
    wp3A[f] = w3a[o*128 + c];
  }
  for (int f = t0; f < 192 * 1024; f += NT) {     // wgT [192][1024]
    int c = f >> 10, o = f & 1023;
    wgT[f] = wg[o*192 + c];
  }
}

// ---------------------------------------------------------------- point norms
__global__ __launch_bounds__(256) void xx_points(const float* __restrict__ pts,
                                                 float* __restrict__ xx)
{
  int t = blockIdx.x * 256 + threadIdx.x;
  if (t < 2 * NPTS) {
    const float* p = pts + (size_t)t * 3;
    xx[t] = p[0]*p[0] + p[1]*p[1] + p[2]*p[2];
  }
}

// ---------------------------------------------------------------- selection
__device__ __forceinline__ void bitonic64_desc_f(float& v, int lane) {
  #pragma unroll
  for (int k = 2; k <= 64; k <<= 1) {
    #pragma unroll
    for (int j = k >> 1; j >= 1; j >>= 1) {
      float o = __shfl_xor(v, j);
      bool take_max = (((lane & k) == 0) == ((lane & j) == 0));
      v = take_max ? fmaxf(v, o) : fminf(v, o);
    }
  }
}

__device__ __forceinline__ void bitonic64_desc_u64(unsigned long long& v, int lane) {
  #pragma unroll
  for (int k = 2; k <= 64; k <<= 1) {
    #pragma unroll
    for (int j = k >> 1; j >= 1; j >>= 1) {
      unsigned long long o = __shfl_xor(v, j);
      bool take_max = (((lane & k) == 0) == ((lane & j) == 0));
      unsigned long long hi = v > o ? v : o;
      unsigned long long lo = v > o ? o : v;
      v = take_max ? hi : lo;
    }
  }
}

// Exact top-20 of one 4096-elem HALF (R10/R11-proven; used by knn3):
__device__ void sel20_half(float* __restrict__ sdh, int half, int lane,
                           float* __restrict__ hv, int* __restrict__ hj,
                           float* __restrict__ cv, int* __restrict__ cj)
{
  float m = -INFINITY;
  const float4* rp = (const float4*)(sdh + lane * 64);
  #pragma unroll
  for (int t = 0; t < 16; ++t) {
    float4 x = rp[(t + lane) & 15];
    m = fmaxf(m, fmaxf(fmaxf(x.x, x.y), fmaxf(x.z, x.w)));
  }
  bitonic64_desc_f(m, lane);
  float That = __shfl(m, 19);

  int base = 0;
  for (int i = 0; i < 64; ++i) {
    float v = sdh[i * 64 + lane];
    bool p = (v >= That);
    unsigned long long mk = __ballot(p);
    if (p) {
      int pos = base + (int)__popcll(mk & ((1ull << lane) - 1ull));
      if (pos < 64) { cv[pos] = v; cj[pos] = i * 64 + lane; }
    }
    base += (int)__popcll(mk);
  }

  if (base <= 64) {
    unsigned long long key = 0ull;
    if (lane < base)
      key = (((unsigned long long)fkey(cv[lane])) << 32) | (unsigned)(~cj[lane]);
    bitonic64_desc_u64(key, lane);
    if (lane < KNN) {
      hv[lane] = funkey((unsigned)(key >> 32));
      hj[lane] = (half << 12) + (int)((~(unsigned)key) & 4095u);
    }
  } else {
    for (int kk = 0; kk < KNN; ++kk) {
      float bv = -INFINITY; int bj = 4096;
      for (int i = 0; i < 64; ++i) {
        float v = sdh[i * 64 + lane];
        if (v > bv) { bv = v; bj = i * 64 + lane; }
      }
      #pragma unroll
      for (int mm = 32; mm >= 1; mm >>= 1) {
        float ov = __shfl_xor(bv, mm); int oj = __shfl_xor(bj, mm);
        if (ov > bv || (ov == bv && oj < bj)) { bv = ov; bj = oj; }
      }
      if (lane == 0) { hv[kk] = bv; hj[kk] = (half << 12) + bj; }
      sdh[bj] = -INFINITY;            // all lanes, same addr/value
    }
  }
}

__device__ __forceinline__ void merge_halves(const float* __restrict__ hv,
                                             const int* __restrict__ hj,
                                             int lane, int* __restrict__ orow)
{
  unsigned long long key = 0ull;
  if (lane < 2 * KNN)
    key = (((unsigned long long)fkey(hv[lane])) << 32) | (unsigned)(~hj[lane]);
  bitonic64_desc_u64(key, lane);
  if (lane < KNN) orow[lane] = (int)((~(unsigned)key) & (NPTS - 1));
}

// Exact top-20 of one 2048-elem QUARTER; returns sorted u64 keys on lanes
// 0..19 (key = (fkey(v)<<32)|~jglobal). Chunks stride-interleaved -> all LDS
// reads conflict-free. Threshold = 20th-largest chunk max (<= true T20).
// Expected candidates ~24, cap 64; exact serial fallback otherwise.
__device__ unsigned long long sel20_quarter(float* __restrict__ sdq, int jbase,
                                            int lane, float* __restrict__ cv,
                                            int* __restrict__ cj)
{
  float m = -INFINITY;
  #pragma unroll 8
  for (int i = 0; i < 32; ++i) m = fmaxf(m, sdq[i * 64 + lane]);
  bitonic64_desc_f(m, lane);
  float That = __shfl(m, 19);

  int base = 0;
  for (int i = 0; i < 32; ++i) {
    float v = sdq[i * 64 + lane];
    bool p = (v >= That);
    unsigned long long mk = __ballot(p);
    if (p) {
      int pos = base + (int)__popcll(mk & ((1ull << lane) - 1ull));
      if (pos < 64) { cv[pos] = v; cj[pos] = jbase + i * 64 + lane; }
    }
    base += (int)__popcll(mk);
  }

  unsigned long long key = 0ull;
  if (base <= 64) {
    if (lane < base)
      key = (((unsigned long long)fkey(cv[lane])) << 32) | (unsigned)(~cj[lane]);
    bitonic64_desc_u64(key, lane);
  } else {
    for (int kk = 0; kk < KNN; ++kk) {
      float bv = -INFINITY; int bj = 2048;
      for (int i = 0; i < 32; ++i) {
        float v = sdq[i * 64 + lane];
        if (v > bv) { bv = v; bj = i * 64 + lane; }
      }
      #pragma unroll
      for (int mm = 32; mm >= 1; mm >>= 1) {
        float ov = __shfl_xor(bv, mm); int oj = __shfl_xor(bj, mm);
        if (ov > bv || (ov == bv && oj < bj)) { bv = ov; bj = oj; }
      }
      if (lane == kk)
        key = (((unsigned long long)fkey(bv)) << 32) | (unsigned)(~(jbase + bj));
      sdq[bj] = -INFINITY;            // all lanes, same addr/value
    }
  }
  return key;
}

// ---------------------------------------------------------------- kNN on xyz
__global__ __launch_bounds__(512, 4) void knn3_kernel(
    const float* __restrict__ pts, const float* __restrict__ xx,
    int* __restrict__ idxout)
{
  __shared__ __align__(16) float sd[4][4096];          // 64 KB
  __shared__ float s_ctr[4][4];
  __shared__ float s_hv[4][2 * KNN];
  __shared__ int   s_hj[4][2 * KNN];
  __shared__ float s_cv[4][64];
  __shared__ int   s_cj[4][64];
  const int tid = threadIdx.x;
  const int b   = blockIdx.x / (NPTS / 4);
  const int r0  = (blockIdx.x % (NPTS / 4)) * 4;
  const size_t rowbase = (size_t)b * NPTS;

  for (int i = tid; i < 12; i += 512)
    s_ctr[i / 3][i % 3] = pts[(rowbase + r0 + i / 3) * 3 + i % 3];
  __syncthreads();

  const float xr0 = xx[rowbase + r0 + 0], xr1 = xx[rowbase + r0 + 1];
  const float xr2 = xx[rowbase + r0 + 2], xr3 = xx[rowbase + r0 + 3];
  const float c00 = s_ctr[0][0], c01 = s_ctr[0][1], c02 = s_ctr[0][2];
  const float c10 = s_ctr[1][0], c11 = s_ctr[1][1], c12 = s_ctr[1][2];
  const float c20 = s_ctr[2][0], c21 = s_ctr[2][1], c22 = s_ctr[2][2];
  const float c30 = s_ctr[3][0], c31 = s_ctr[3][1], c32 = s_ctr[3][2];
  const int wid = tid >> 6, lane = tid & 63;

  #pragma unroll 1
  for (int h = 0; h < 2; ++h) {
    for (int jl = tid; jl < 4096; jl += 512) {
      const int jg = (h << 12) + jl;
      const float* fj = pts + (rowbase + jg) * 3;
      const float f0 = fj[0], f1 = fj[1], f2 = fj[2];
      const float xj = xx[rowbase + jg];
      sd[0][jl] = 2.f*(f0*c00 + f1*c01 + f2*c02) - xr0 - xj;
      sd[1][jl] = 2.f*(f0*c10 + f1*c11 + f2*c12) - xr1 - xj;
      sd[2][jl] = 2.f*(f0*c20 + f1*c21 + f2*c22) - xr2 - xj;
      sd[3][jl] = 2.f*(f0*c30 + f1*c31 + f2*c32) - xr3 - xj;
    }
    __syncthreads();
    if (wid < 4)
      sel20_half(sd[wid], h, lane, &s_hv[wid][h * KNN], &s_hj[wid][h * KNN],
                 s_cv[wid], s_cj[wid]);
    __syncthreads();
  }
  if (wid < 4)
    merge_halves(s_hv[wid], s_hj[wid], lane, idxout + (rowbase + r0 + wid) * KNN);
}

// ---------------------------------------------------------------- kNN on 64-ch features
#define ACC4(A, C) \
  A.x += v0.x*C.x + v1.x*C.y + v2.x*C.z + v3.x*C.w; \
  A.y += v0.y*C.x + v1.y*C.y + v2.y*C.z + v3.y*C.w; \
  A.z += v0.z*C.x + v1.z*C.y + v2.z*C.z + v3.z*C.w; \
  A.w += v0.w*C.x + v1.w*C.y + v2.w*C.z + v3.w*C.w;

__global__ __launch_bounds__(512, 4) void knn64_kernel(
    const float* __restrict__ featT, const float* __restrict__ xx,
    int* __restrict__ idxout)
{
  __shared__ __align__(16) float sd[8][2048];          // 64 KB
  __shared__ __align__(16) float s_ctr[8][64];         // 2 KB
  __shared__ float s_cv[8][64];
  __shared__ int   s_cj[8][64];
  const int tid = threadIdx.x;
  const int bid = blockIdx.x;
  const int b   = (bid & 7) >> 2;                      // XCD-batch swizzle
  const int r0  = (((bid >> 3) << 2) + (bid & 3)) * 8; // bijective rowgrp
  const size_t tb = (size_t)b * 64 * NPTS;
  const size_t rowbase = (size_t)b * NPTS;

  s_ctr[tid >> 6][tid & 63] = featT[tb + (size_t)(tid & 63) * NPTS + r0 + (tid >> 6)];
  __syncthreads();

  const int wid = tid >> 6, lane = tid & 63;
  float xr[8];
  #pragma unroll
  for (int r = 0; r < 8; ++r) xr[r] = xx[rowbase + r0 + r];
  const float4* ct0 = (const float4*)s_ctr[0];
  const float4* ct1 = (const float4*)s_ctr[1];
  const float4* ct2 = (const float4*)s_ctr[2];
  const float4* ct3 = (const float4*)s_ctr[3];
  const float4* ct4 = (const float4*)s_ctr[4];
  const float4* ct5 = (const float4*)s_ctr[5];
  const float4* ct6 = (const float4*)s_ctr[6];
  const float4* ct7 = (const float4*)s_ctr[7];

  unsigned long long runkey = 0ull;

  #pragma unroll 1
  for (int h = 0; h < 4; ++h) {
    const int jl = (wid << 8) + (lane << 2);            // 4 points per lane
    const int jg = (h << 11) + jl;
    float4 a0 = {0.f,0.f,0.f,0.f}, a1 = a0, a2 = a0, a3 = a0;
    float4 a4 = a0, a5 = a0, a6 = a0, a7 = a0;
    const float* fp0 = featT + tb + jg;
    #pragma unroll 2
    for (int c4 = 0; c4 < 16; ++c4) {
      const float* fp = fp0 + (size_t)(c4 * 4) * NPTS;
      float4 v0 = *(const float4*)(fp);
      float4 v1 = *(const float4*)(fp + NPTS);
      float4 v2 = *(const float4*)(fp + 2 * NPTS);
      float4 v3 = *(const float4*)(fp + 3 * NPTS);
      float4 c;
      c = ct0[c4]; ACC4(a0, c);
      c = ct1[c4]; ACC4(a1, c);
      c = ct2[c4]; ACC4(a2, c);
      c = ct3[c4]; ACC4(a3, c);
      c = ct4[c4]; ACC4(a4, c);
      c = ct5[c4]; ACC4(a5, c);
      c = ct6[c4]; ACC4(a6, c);
      c = ct7[c4]; ACC4(a7, c);
    }
    const float4 xv = *(const float4*)(xx + rowbase + jg);
    float4 s;
    #define STORE_ROW(A, R) \
      s.x = 2.f*A.x - xr[R] - xv.x; s.y = 2.f*A.y - xr[R] - xv.y; \
      s.z = 2.f*A.z - xr[R] - xv.z; s.w = 2.f*A.w - xr[R] - xv.w; \
      *(float4*)&sd[R][jl] = s;
    STORE_ROW(a0, 0); STORE_ROW(a1, 1); STORE_ROW(a2, 2); STORE_ROW(a3, 3);
    STORE_ROW(a4, 4); STORE_ROW(a5, 5); STORE_ROW(a6, 6); STORE_ROW(a7, 7);
    #undef STORE_ROW
    __syncthreads();

    unsigned long long pk = sel20_quarter(sd[wid], h << 11, lane,
                                          s_cv[wid], s_cj[wid]);
    unsigned long long nk = __shfl(pk, lane - 20);
    unsigned long long mkey = (lane < 20) ? runkey
                            : ((lane < 40) ? nk : 0ull);
    bitonic64_desc_u64(mkey, lane);
    runkey = mkey;
    __syncthreads();
  }
  if (lane < KNN)
    idxout[(rowbase + r0 + wid) * KNN + lane] =
        (int)((~(unsigned)runkey) & (NPTS - 1));
}

// ---------------------------------------------------------------- fused EdgeConv
// 8 points/block (512 threads, wave = point): 2 blocks/CU at 75KB LDS ->
// 16 waves/CU (was 1 block x 4 waves) to hide gather latency + barriers.
// launch_bounds(512,2) caps VGPR at 256 (body needs ~90; tripwire WRITE_SIZE).
template<int D, bool HASB, bool WAUX>
__global__ __launch_bounds__(512, 2) void fused_conv(
    const float* __restrict__ feat, int fstride, int foff,
    const int* __restrict__ idx,
    const float4* __restrict__ wAp, const float* __restrict__ sa, const float* __restrict__ ba,
    const float4* __restrict__ wBp, const float* __restrict__ sb, const float* __restrict__ bb,
    float* __restrict__ outbuf, int ooff, float* __restrict__ xxout,
    float* __restrict__ featT)
{
  constexpr int CHA  = (D == 64) ? 32 : 2;   // float4 chunks of 2D (padded)
  constexpr int CHA4 = CHA * 4;
  __shared__ float4 s_wA[CHA * 64];                      // 32KB / 2KB
  __shared__ float4 s_wB[HASB ? 16 * 64 : 1];            // 16KB
  __shared__ __align__(16) float4 s_g[8 * KC * CHA];     // 16KB / 1KB
  __shared__ __align__(16) float  s_h1[HASB ? 8 * KC * 64 : 4];  // 8KB
  __shared__ float s_ctr[8][(D > 4) ? D : 4];            // 2KB
  __shared__ float s_sa[64], s_ba[64], s_sb[64], s_bb[64];

  const int tid = threadIdx.x;
  const int p = tid >> 6, o = tid & 63;                  // wave = point
  const int b  = blockIdx.x / (NPTS / 8);
  const int p0 = (blockIdx.x % (NPTS / 8)) * 8;
  const size_t rowbase = (size_t)b * NPTS;

  for (int i = tid; i < CHA * 64; i += 512) s_wA[i] = wAp[i];
  if (HASB) for (int i = tid; i < 16 * 64; i += 512) s_wB[i] = wBp[i];
  if (tid < 64) {
    s_sa[tid] = sa[tid]; s_ba[tid] = ba[tid];
    if (HASB) { s_sb[tid] = sb[tid]; s_bb[tid] = bb[tid]; }
  }
  for (int i = tid; i < 8 * D; i += 512)
    s_ctr[i / D][i % D] = feat[(rowbase + p0 + (i / D)) * fstride + foff + (i % D)];
  __syncthreads();

  float* s_gf = (float*)s_g;
  float hmax = -INFINITY;
  for (int kc = 0; kc < KNN / KC; ++kc) {
    for (int s = tid; s < 8 * KC * CHA4; s += 512) {
      int pp = s / (KC * CHA4);
      int rr = s - pp * (KC * CHA4);
      int kk = rr / CHA4;
      int c  = rr - kk * CHA4;
      int nb = idx[(rowbase + p0 + pp) * KNN + kc * KC + kk];
      float v;
      if (D == 64) {
        v = (c < 64) ? (feat[(rowbase + nb) * fstride + foff + c] - s_ctr[pp][c])
                     : s_ctr[pp][c - 64];
      } else {
        if (c < 3)      v = feat[(rowbase + nb) * 3 + c] - s_ctr[pp][c];
        else if (c < 6) v = s_ctr[pp][c - 3];
        else            v = 0.f;
      }
      s_gf[s] = v;
    }
    __syncthreads();

    float acc[KC];
    #pragma unroll
    for (int kk = 0; kk < KC; ++kk) acc[kk] = 0.f;
    for (int c4 = 0; c4 < CHA; ++c4) {
      float4 w = s_wA[c4 * 64 + o];
      #pragma unroll
      for (int kk = 0; kk < KC; ++kk) {
        float4 g = s_g[(p * KC + kk) * CHA + c4];
        acc[kk] += w.x*g.x + w.y*g.y + w.z*g.z + w.w*g.w;
      }
    }
    if (HASB) {
      #pragma unroll
      for (int kk = 0; kk < KC; ++kk)
        s_h1[(p * KC + kk) * 64 + o] = lrelu(acc[kk] * s_sa[o] + s_ba[o]);
      __syncthreads();
      float acc2[KC];
      #pragma unroll
      for (int kk = 0; kk < KC; ++kk) acc2[kk] = 0.f;
      const float4* s_h14 = (const float4*)s_h1;
      for (int c4 = 0; c4 < 16; ++c4) {
        float4 w = s_wB[c4 * 64 + o];
        #pragma unroll
        for (int kk = 0; kk < KC; ++kk) {
          float4 h = s_h14[(p * KC + kk) * 16 + c4];
          acc2[kk] += w.x*h.x + w.y*h.y + w.z*h.z + w.w*h.w;
        }
      }
      #pragma unroll
      for (int kk = 0; kk < KC; ++kk)
        hmax = fmaxf(hmax, lrelu(acc2[kk] * s_sb[o] + s_bb[o]));
      __syncthreads();
    } else {
      #pragma unroll
      for (int kk = 0; kk < KC; ++kk)
        hmax = fmaxf(hmax, lrelu(acc[kk] * s_sa[o] + s_ba[o]));
      __syncthreads();
    }
  }
  outbuf[(rowbase + p0 + p) * 192 + ooff + o] = hmax;
  if (WAUX) {
    featT[(size_t)b * 64 * NPTS + (size_t)o * NPTS + (p0 + p)] = hmax;
    float ss = hmax * hmax;
    #pragma unroll
    for (int m = 1; m < 64; m <<= 1) ss += __shfl_xor(ss, m);
    if (o == 0) xxout[rowbase + p0 + p] = ss;
  }
}

// ---------------------------------------------------------------- final 192->1024
__global__ __launch_bounds__(256) void init_gmax(unsigned* __restrict__ g)
{
  int t = blockIdx.x * 256 + threadIdx.x;
  if (t < 2048) g[t] = fkey(-1e30f);
}

__global__ __launch_bounds__(256) void final_kernel(
    const float* __restrict__ cat, const float* __restrict__ wgT,
    const float* __restrict__ sg, const float* __restrict__ bg,
    unsigned* __restrict__ gmax)
{
  const int tid = threadIdx.x;
  const int chunk = blockIdx.x & 15;
  const int grp   = blockIdx.x >> 4;
  const int pt = grp * 256 + tid;
  const int b  = pt >> 13;
  const float4* crow = (const float4*)(cat + (size_t)pt * 192);
  float acc[64];
  #pragma unroll
  for (int o = 0; o < 64; ++o) acc[o] = 0.f;
  for (int c4 = 0; c4 < 48; ++c4) {
    float4 cv = crow[c4];
    const float* w0 = wgT + (size_t)(c4 * 4) * 1024 + chunk * 64;
    const float* w1 = w0 + 1024;
    const float* w2 = w1 + 1024;
    const float* w3 = w2 + 1024;
    #pragma unroll
    for (int o = 0; o < 64; ++o)
      acc[o] += cv.x*w0[o] + cv.y*w1[o] + cv.z*w2[o] + cv.w*w3[o];
  }
  const int lane = tid & 63;
  #pragma unroll
  for (int o = 0; o < 64; ++o) {
    int ch = chunk * 64 + o;
    float h = lrelu(acc[o] * sg[ch] + bg[ch]);
    #pragma unroll
    for (int m = 1; m < 64; m <<= 1) h = fmaxf(h, __shfl_xor(h, m));
    if (lane == 0) atomicMax(&gmax[b * 1024 + ch], fkey(h));
  }
}

// Output is FP32: [2][1024][8192] floats. (Also fully overwrites the featT
// scratch region that lived in d_out during the pipeline.)
__global__ __launch_bounds__(256) void bcast_kernel(const unsigned* __restrict__ gmax,
                                                    float* __restrict__ out)
{
  int t = blockIdx.x * 256 + threadIdx.x;   // each thread: 4 floats = 16B
  int bo = t >> 11;
  float v = funkey(gmax[bo]);
  float4 w; w.x = v; w.y = v; w.z = v; w.w = v;
  ((float4*)out)[t] = w;
}

// ---------------------------------------------------------------- launch
extern "C" void kernel_launch(void* const* d_in, const int* in_sizes, int n_in,
                              void* d_out, int out_size, void* d_ws, size_t ws_size,
                              hipStream_t stream)
{
  const float* points = (const float*)d_in[0];
  const float* w1a = (const float*)d_in[1];  const float* s1a = (const float*)d_in[2];  const float* b1a = (const float*)d_in[3];
  const float* w1b = (const float*)d_in[4];  const float* s1b = (const float*)d_in[5];  const float* b1b = (const float*)d_in[6];
  const float* w2a = (const float*)d_in[7];  const float* s2a = (const float*)d_in[8];  const float* b2a = (const float*)d_in[9];
  const float* w2b = (const float*)d_in[10]; const float* s2b = (const float*)d_in[11]; const float* b2b = (const float*)d_in[12];
  const float* w3a = (const float*)d_in[13]; const float* s3a = (const float*)d_in[14]; const float* b3a = (const float*)d_in[15];
  const float* wg  = (const float*)d_in[16]; const float* sg  = (const float*)d_in[17]; const float* bg  = (const float*)d_in[18];

  char* ws = (char*)d_ws;
  float*    cat   = (float*)(ws);                   // [2*8192][192]  12,582,912 B
  float*    xxbuf = (float*)(ws + 12582912);        // [2*8192]           65,536 B
  int*      idxb  = (int*)  (ws + 12648448);        // [2*8192][20]    1,310,720 B
  float*    wp1A  = (float*)(ws + 13959168);
  float*    wp1B  = (float*)(ws + 13961216);
  float*    wp2A  = (float*)(ws + 13977600);
  float*    wp2B  = (float*)(ws + 14010368);
  float*    wp3A  = (float*)(ws + 14026752);
  float*    wgT   = (float*)(ws + 14059520);
  unsigned* gmax  = (unsigned*)(ws + 14845952);
  const size_t WS_NEED = 14854144;
  if (ws_size < WS_NEED || n_in != 19) return;

  // featT scratch [2][64][8192] fp32 = 4 MB lives in d_out (67 MB), which is
  // fully overwritten by bcast_kernel at the end of every call.
  float* featT = (float*)d_out;

  prep_kernel<<<256, 256, 0, stream>>>(w1a, w1b, w2a, w2b, w3a, wg,
                                       wp1A, wp1B, wp2A, wp2B, wp3A, wgT);
  xx_points<<<64, 256, 0, stream>>>(points, xxbuf);
  knn3_kernel<<<4096, 512, 0, stream>>>(points, xxbuf, idxb);
  fused_conv<3, true, true><<<2048, 512, 0, stream>>>(
      points, 3, 0, idxb, (const float4*)wp1A, s1a, b1a,
      (const float4*)wp1B, s1b, b1b, cat, 0, xxbuf, featT);
  knn64_kernel<<<2048, 512, 0, stream>>>(featT, xxbuf, idxb);
  fused_conv<64, true, true><<<2048, 512, 0, stream>>>(
      cat, 192, 0, idxb, (const float4*)wp2A, s2a, b2a,
      (const float4*)wp2B, s2b, b2b, cat, 64, xxbuf, featT);
  knn64_kernel<<<2048, 512, 0, stream>>>(featT, xxbuf, idxb);
  fused_conv<64, false, false><<<2048, 512, 0, stream>>>(
      cat, 192, 64, idxb, (const float4*)wp3A, s3a, b3a,
      nullptr, nullptr, nullptr, cat, 128, nullptr, nullptr);
  init_gmax<<<8, 256, 0, stream>>>(gmax);
  final_kernel<<<1024, 256, 0, stream>>>(cat, wgT, sg, bg, gmax);
  bcast_kernel<<<16384, 256, 0, stream>>>(gmax, (float*)d_out);
}